// Round 1
// baseline (1155.551 us; speedup 1.0000x reference)
//
#include <hip/hip_runtime.h>
#include <math.h>

// Problem constants
#define M_TOK   25600     // N*L = 25 * 1024 tokens
#define DCH     128
#define L_SP    1024
#define NB      25

// ---------------------------------------------------------------------------
// Generic fp32 GEMM:  out[M x N] (+=) A[M x K] * W[N x K]^T
// 64x64 tile, 256 threads, 4x4 micro-tile per thread.
// IM2COL: A is the raw buffer [64][25][32][32]; A-row t, col k=(cc*9+tap)
//         materialized on the fly (3x3 zero-padded patch).
// TROUT : write out[n*M + m] (for final channel-major output).
// ADD   : out += (residual accumulate).
// ---------------------------------------------------------------------------
template <bool ADD, bool TROUT, bool IM2COL>
__global__ __launch_bounds__(256) void gemm_nt(const float* __restrict__ A,
                                               const float* __restrict__ W,
                                               float* __restrict__ out,
                                               int M, int N, int K) {
    __shared__ __align__(16) float As[16][68];
    __shared__ __align__(16) float Ws[16][68];

    const int bm = blockIdx.x * 64;
    const int bn = blockIdx.y * 64;
    const int tid = threadIdx.x;
    const int tm = (tid & 15) * 4;
    const int tn = (tid >> 4) * 4;

    float acc[4][4] = {};

    for (int k0 = 0; k0 < K; k0 += 16) {
        __syncthreads();
#pragma unroll
        for (int e = 0; e < 4; ++e) {
            int li = tid + e * 256;          // 0..1023
            int mm = li >> 4;                // 0..63
            int kk = li & 15;
            int k = k0 + kk;
            int gm = bm + mm;
            float av;
            if (IM2COL) {
                // k = cc*9 + tap, tap = i*3 + j
                int cc = k / 9;
                int tap = k - cc * 9;
                int ti = tap / 3;
                int tj = tap - ti * 3;
                int yy = ((gm >> 5) & 31) + ti - 1;
                int xx = (gm & 31) + tj - 1;
                int nn = gm >> 10;
                av = (yy >= 0 && yy < 32 && xx >= 0 && xx < 32)
                         ? A[(size_t)cc * M_TOK + ((size_t)nn << 10) + (yy << 5) + xx]
                         : 0.f;
            } else {
                av = (k < K) ? A[(size_t)gm * K + k] : 0.f;
            }
            As[kk][mm] = av;
            int gn = bn + mm;
            Ws[kk][mm] = (gn < N && k < K) ? W[(size_t)gn * K + k] : 0.f;
        }
        __syncthreads();
#pragma unroll
        for (int kk = 0; kk < 16; ++kk) {
            float a[4], b[4];
            *(float4*)a = *(const float4*)&As[kk][tm];
            *(float4*)b = *(const float4*)&Ws[kk][tn];
#pragma unroll
            for (int i = 0; i < 4; ++i)
#pragma unroll
                for (int j = 0; j < 4; ++j)
                    acc[i][j] += a[i] * b[j];
        }
    }

#pragma unroll
    for (int i = 0; i < 4; ++i) {
        int gm = bm + tm + i;
#pragma unroll
        for (int j = 0; j < 4; ++j) {
            int gn = bn + tn + j;
            if (gn < N) {
                size_t oi = TROUT ? ((size_t)gn * M + gm) : ((size_t)gm * N + gn);
                if (ADD) out[oi] += acc[i][j];
                else     out[oi] = acc[i][j];
            }
        }
    }
}

// ---------------------------------------------------------------------------
// LayerNorm over D=128, one 64-lane wave per token (4 tokens / block)
// ---------------------------------------------------------------------------
__global__ __launch_bounds__(256) void ln_k(const float* __restrict__ in,
                                            const float* __restrict__ w,
                                            const float* __restrict__ b,
                                            float* __restrict__ out) {
    int t = blockIdx.x * 4 + (threadIdx.x >> 6);
    int lane = threadIdx.x & 63;
    const float* row = in + (size_t)t * 128 + lane * 2;
    float2 v = *(const float2*)row;
    float s = v.x + v.y;
    float sq = v.x * v.x + v.y * v.y;
#pragma unroll
    for (int off = 32; off > 0; off >>= 1) {
        s += __shfl_xor(s, off);
        sq += __shfl_xor(sq, off);
    }
    float mean = s * (1.f / 128.f);
    float var = sq * (1.f / 128.f) - mean * mean;
    float rstd = rsqrtf(var + 1e-5f);
    float2 wv = *(const float2*)(w + lane * 2);
    float2 bv = *(const float2*)(b + lane * 2);
    float2 o;
    o.x = (v.x - mean) * rstd * wv.x + bv.x;
    o.y = (v.y - mean) * rstd * wv.y + bv.y;
    *(float2*)(out + (size_t)t * 128 + lane * 2) = o;
}

// ---------------------------------------------------------------------------
// Depthwise 3x3 conv, zero pad, layout [token][CH] channel-fastest
// ---------------------------------------------------------------------------
template <int CH>
__global__ __launch_bounds__(256) void dwconv_k(const float* __restrict__ in,
                                                const float* __restrict__ w,
                                                float* __restrict__ out) {
    size_t idx = (size_t)blockIdx.x * 256 + threadIdx.x;   // t*CH + ch
    int ch = (int)(idx % CH);
    size_t t = idx / CH;
    int l = (int)(t & 1023);
    size_t nb = (t >> 10) << 10;
    int y = l >> 5, x = l & 31;
    float acc = 0.f;
#pragma unroll
    for (int i = 0; i < 3; ++i) {
        int yy = y + i - 1;
        if (yy < 0 || yy >= 32) continue;
#pragma unroll
        for (int j = 0; j < 3; ++j) {
            int xx = x + j - 1;
            if (xx < 0 || xx >= 32) continue;
            acc += in[(nb + (yy << 5) + xx) * CH + ch] * w[ch * 9 + i * 3 + j];
        }
    }
    out[idx] = acc;
}

// ---------------------------------------------------------------------------
// L2-normalize q and k head-vectors in place.  one thread = one 32-float group
// groups: cols g*32, g in 0..7  (q heads 0..3, k heads 0..3)
// ---------------------------------------------------------------------------
__global__ __launch_bounds__(256) void l2n_k(float* __restrict__ qkv) {
    size_t idx = (size_t)blockIdx.x * 256 + threadIdx.x;
    size_t t = idx >> 3;
    int g = (int)(idx & 7);
    float* p = qkv + t * 384 + g * 32;
    float ss = 0.f;
    float4 v[8];
#pragma unroll
    for (int c = 0; c < 8; ++c) {
        v[c] = *(const float4*)(p + c * 4);
        ss += v[c].x * v[c].x + v[c].y * v[c].y + v[c].z * v[c].z + v[c].w * v[c].w;
    }
    float sc = 1.f / fmaxf(sqrtf(ss), 1e-12f);
#pragma unroll
    for (int c = 0; c < 8; ++c) {
        float4 o = v[c];
        o.x *= sc; o.y *= sc; o.z *= sc; o.w *= sc;
        *(float4*)(p + c * 4) = o;
    }
}

// ---------------------------------------------------------------------------
// Flash-style attention.  grid (N*HEADS, 2), 256 threads.
// Thread owns 2 q-rows (r0, r0+256) fully in registers; K/V staged in LDS
// in 64-row chunks; branchy online softmax (rescale only when max grows).
// qkv layout: [t][384] = [q 0..127 | k 128..255 | v 256..383], head-major 32.
// out: [t][128] token-major.
// ---------------------------------------------------------------------------
__global__ __launch_bounds__(256) void attn_k(const float* __restrict__ qkv,
                                              const float* __restrict__ temp,
                                              float* __restrict__ outp) {
    const int n = blockIdx.x >> 2;
    const int hd = blockIdx.x & 3;
    const size_t base = (size_t)n * 1024 * 384;
    const int r0 = blockIdx.y * 512 + threadIdx.x;
    const float tscale = temp[hd];

    float q0[32], q1[32], o0[32], o1[32];
    float m0 = -1e30f, m1 = -1e30f, s0 = 0.f, s1 = 0.f;

    {
        const float* qp0 = qkv + base + (size_t)r0 * 384 + hd * 32;
        const float* qp1 = qp0 + (size_t)256 * 384;
#pragma unroll
        for (int c = 0; c < 8; ++c) {
            float4 a = *(const float4*)(qp0 + c * 4);
            float4 b = *(const float4*)(qp1 + c * 4);
            q0[c * 4 + 0] = a.x; q0[c * 4 + 1] = a.y; q0[c * 4 + 2] = a.z; q0[c * 4 + 3] = a.w;
            q1[c * 4 + 0] = b.x; q1[c * 4 + 1] = b.y; q1[c * 4 + 2] = b.z; q1[c * 4 + 3] = b.w;
        }
    }
#pragma unroll
    for (int c = 0; c < 32; ++c) { o0[c] = 0.f; o1[c] = 0.f; }

    __shared__ __align__(16) float Ks[64][36];
    __shared__ __align__(16) float Vs[64][36];

    for (int j0 = 0; j0 < 1024; j0 += 64) {
        __syncthreads();
#pragma unroll
        for (int e = 0; e < 2; ++e) {
            int li = threadIdx.x + e * 256;   // 0..511
            int row = li >> 3, c4 = li & 7;
            const float* kp = qkv + base + (size_t)(j0 + row) * 384 + 128 + hd * 32 + c4 * 4;
            *(float4*)&Ks[row][c4 * 4] = *(const float4*)kp;
            *(float4*)&Vs[row][c4 * 4] = *(const float4*)(kp + 128);
        }
        __syncthreads();
        for (int j = 0; j < 64; ++j) {
            float d0 = 0.f, d1 = 0.f;
#pragma unroll
            for (int c = 0; c < 8; ++c) {
                float4 kk = *(const float4*)&Ks[j][c * 4];
                d0 += q0[c * 4 + 0] * kk.x + q0[c * 4 + 1] * kk.y +
                      q0[c * 4 + 2] * kk.z + q0[c * 4 + 3] * kk.w;
                d1 += q1[c * 4 + 0] * kk.x + q1[c * 4 + 1] * kk.y +
                      q1[c * 4 + 2] * kk.z + q1[c * 4 + 3] * kk.w;
            }
            d0 *= tscale; d1 *= tscale;
            float p0, p1;
            if (d0 <= m0) {
                p0 = __expf(d0 - m0);
            } else {
                float cr = __expf(m0 - d0);
                s0 *= cr;
#pragma unroll
                for (int c = 0; c < 32; ++c) o0[c] *= cr;
                m0 = d0; p0 = 1.f;
            }
            if (d1 <= m1) {
                p1 = __expf(d1 - m1);
            } else {
                float cr = __expf(m1 - d1);
                s1 *= cr;
#pragma unroll
                for (int c = 0; c < 32; ++c) o1[c] *= cr;
                m1 = d1; p1 = 1.f;
            }
            s0 += p0; s1 += p1;
#pragma unroll
            for (int c = 0; c < 8; ++c) {
                float4 vv = *(const float4*)&Vs[j][c * 4];
                o0[c * 4 + 0] += p0 * vv.x; o0[c * 4 + 1] += p0 * vv.y;
                o0[c * 4 + 2] += p0 * vv.z; o0[c * 4 + 3] += p0 * vv.w;
                o1[c * 4 + 0] += p1 * vv.x; o1[c * 4 + 1] += p1 * vv.y;
                o1[c * 4 + 2] += p1 * vv.z; o1[c * 4 + 3] += p1 * vv.w;
            }
        }
    }
    float i0 = 1.f / s0, i1 = 1.f / s1;
    float* op0 = outp + ((size_t)n * 1024 + r0) * 128 + hd * 32;
    float* op1 = op0 + (size_t)256 * 128;
#pragma unroll
    for (int c = 0; c < 8; ++c) {
        float4 a, b;
        a.x = o0[c * 4 + 0] * i0; a.y = o0[c * 4 + 1] * i0;
        a.z = o0[c * 4 + 2] * i0; a.w = o0[c * 4 + 3] * i0;
        b.x = o1[c * 4 + 0] * i1; b.y = o1[c * 4 + 1] * i1;
        b.z = o1[c * 4 + 2] * i1; b.w = o1[c * 4 + 3] * i1;
        *(float4*)(op0 + c * 4) = a;
        *(float4*)(op1 + c * 4) = b;
    }
}

// ---------------------------------------------------------------------------
// GDFN: two depthwise 3x3 convs (ch, ch+340) + exact gelu gate, writes [t][340]
// ---------------------------------------------------------------------------
__global__ __launch_bounds__(256) void gdfn_k(const float* __restrict__ in,
                                              const float* __restrict__ w,
                                              float* __restrict__ out) {
    size_t idx = (size_t)blockIdx.x * 256 + threadIdx.x;   // t*340 + ch
    int ch = (int)(idx % 340);
    size_t t = idx / 340;
    int l = (int)(t & 1023);
    size_t nb = (t >> 10) << 10;
    int y = l >> 5, x = l & 31;
    float a1 = 0.f, a2 = 0.f;
    const float* w1 = w + ch * 9;
    const float* w2 = w + (ch + 340) * 9;
#pragma unroll
    for (int i = 0; i < 3; ++i) {
        int yy = y + i - 1;
        if (yy < 0 || yy >= 32) continue;
#pragma unroll
        for (int j = 0; j < 3; ++j) {
            int xx = x + j - 1;
            if (xx < 0 || xx >= 32) continue;
            const float* p = in + (nb + (yy << 5) + xx) * 680;
            a1 += p[ch] * w1[i * 3 + j];
            a2 += p[ch + 340] * w2[i * 3 + j];
        }
    }
    float g = 0.5f * a1 * (1.f + erff(a1 * 0.70710678118f));
    out[idx] = g * a2;
}

// ---------------------------------------------------------------------------
extern "C" void kernel_launch(void* const* d_in, const int* in_sizes, int n_in,
                              void* d_out, int out_size, void* d_ws, size_t ws_size,
                              hipStream_t stream) {
    const float* buffer      = (const float*)d_in[0];
    const float* mlp_w       = (const float*)d_in[1];
    const float* ln_attn_w   = (const float*)d_in[2];
    const float* ln_attn_b   = (const float*)d_in[3];
    const float* ln_ffn_w    = (const float*)d_in[4];
    const float* ln_ffn_b    = (const float*)d_in[5];
    const float* qkv_w       = (const float*)d_in[6];
    const float* qkv_dw_w    = (const float*)d_in[7];
    const float* temperature = (const float*)d_in[8];
    const float* proj_attn_w = (const float*)d_in[9];
    const float* ffn_in_w    = (const float*)d_in[10];
    const float* ffn_dw_w    = (const float*)d_in[11];
    const float* ffn_out_w   = (const float*)d_in[12];
    const float* proj3d_w    = (const float*)d_in[13];
    float* out = (float*)d_out;

    const size_t M = M_TOK;
    float* ws = (float*)d_ws;
    // workspace layout (floats); total 43,622,400 floats = 174.5 MB
    float* F1   = ws;                       // [M*680] ffn hidden (pre-dw)
    float* tok  = F1   + M * 680;           // [M*128]
    float* Abuf = tok  + M * 128;           // [M*128] LN out / attn out
    float* Bbuf = Abuf + M * 128;           // [M*384] qkv pre-dw / G [M*340]
    float* Cbuf = Bbuf + M * 384;           // [M*384] qkv post-dw (q,k l2normed)

    dim3 blk(256);

    // 1. SAI2Token: tok = im2col(buffer) @ mlp_w^T     [M x 128], K=576
    gemm_nt<false, false, true><<<dim3(400, 2), blk, 0, stream>>>(
        buffer, mlp_w, tok, (int)M, 128, 576);

    // 2. LN(attn)
    ln_k<<<dim3(M / 4), blk, 0, stream>>>(tok, ln_attn_w, ln_attn_b, Abuf);

    // 3. qkv 1x1: B = A @ qkv_w^T   [M x 384], K=128
    gemm_nt<false, false, false><<<dim3(400, 6), blk, 0, stream>>>(
        Abuf, qkv_w, Bbuf, (int)M, 384, 128);

    // 4. qkv depthwise 3x3: C = dw(B)
    dwconv_k<384><<<dim3((M * 384) / 256), blk, 0, stream>>>(Bbuf, qkv_dw_w, Cbuf);

    // 5. l2norm q,k in place
    l2n_k<<<dim3((M * 8) / 256), blk, 0, stream>>>(Cbuf);

    // 6. attention -> Abuf [M x 128]
    attn_k<<<dim3(100, 2), blk, 0, stream>>>(Cbuf, temperature, Abuf);

    // 7. proj_attn + residual: tok += A @ proj_attn_w^T   K=128
    gemm_nt<true, false, false><<<dim3(400, 2), blk, 0, stream>>>(
        Abuf, proj_attn_w, tok, (int)M, 128, 128);

    // 8. LN(ffn)
    ln_k<<<dim3(M / 4), blk, 0, stream>>>(tok, ln_ffn_w, ln_ffn_b, Abuf);

    // 9. ffn_in 1x1: F1 = A @ ffn_in_w^T   [M x 680], K=128
    gemm_nt<false, false, false><<<dim3(400, 11), blk, 0, stream>>>(
        Abuf, ffn_in_w, F1, (int)M, 680, 128);

    // 10. GDFN dw + gelu gate -> G (reuse Bbuf) [M x 340]
    gdfn_k<<<dim3((M * 340) / 256), blk, 0, stream>>>(F1, ffn_dw_w, Bbuf);

    // 11. ffn_out + residual: tok += G @ ffn_out_w^T   K=340
    gemm_nt<true, false, false><<<dim3(400, 2), blk, 0, stream>>>(
        Bbuf, ffn_out_w, tok, (int)M, 128, 340);

    // 12. Token2SAI: out[o*M + t] = tok @ proj3d_w^T   [M x 64], K=128
    gemm_nt<false, true, false><<<dim3(400, 1), blk, 0, stream>>>(
        tok, proj3d_w, out, (int)M, 64, 128);
}

// Round 2
// 461.894 us; speedup vs baseline: 2.5018x; 2.5018x over previous
//
#include <hip/hip_runtime.h>
#include <math.h>

#define M_TOK 25600   // 25 images * 1024 tokens

typedef __attribute__((ext_vector_type(8))) short bf16x8;
typedef __attribute__((ext_vector_type(4))) float f32x4;
typedef __attribute__((ext_vector_type(4))) int   i32x4;
typedef __attribute__((ext_vector_type(2))) int   i32x2;

__device__ __forceinline__ unsigned short f2b(float x) {
    unsigned u = __builtin_bit_cast(unsigned, x);
    return (unsigned short)((u + 0x7fffu + ((u >> 16) & 1u)) >> 16);
}
__device__ __forceinline__ float b2f(unsigned short h) {
    unsigned u = ((unsigned)h) << 16;
    return __builtin_bit_cast(float, u);
}

// ---------------------------------------------------------------------------
// Weight fp32->bf16 conversion (6 matrices, concatenated destination)
// ---------------------------------------------------------------------------
__global__ __launch_bounds__(256) void cvtw_k(const float* __restrict__ s0, const float* __restrict__ s1,
                                              const float* __restrict__ s2, const float* __restrict__ s3,
                                              const float* __restrict__ s4, const float* __restrict__ s5,
                                              short* __restrict__ dst) {
    int i = blockIdx.x * 256 + threadIdx.x;      // < 278016
    const float* s; int off;
    if      (i < 73728)  { s = s0; off = i; }
    else if (i < 122880) { s = s1; off = i - 73728; }
    else if (i < 139264) { s = s2; off = i - 122880; }
    else if (i < 226304) { s = s3; off = i - 139264; }
    else if (i < 269824) { s = s4; off = i - 226304; }
    else                 { s = s5; off = i - 269824; }
    dst[i] = (short)f2b(s[off]);
}

// ---------------------------------------------------------------------------
// im2col 3x3 (zero pad) -> bf16 patch matrix [M][576], k = cc*9 + (i*3+j)
// ---------------------------------------------------------------------------
__global__ __launch_bounds__(256) void unfold_k(const float* __restrict__ buf, short* __restrict__ P) {
    int idx = blockIdx.x * 256 + threadIdx.x;    // < M*576
    int kk = idx % 576;
    int t  = idx / 576;
    int cc = kk / 9, tap = kk - cc * 9;
    int ti = tap / 3, tj = tap - ti * 3;
    int l = t & 1023, n = t >> 10;
    int y = (l >> 5) + ti - 1, x = (l & 31) + tj - 1;
    float v = (y >= 0 && y < 32 && x >= 0 && x < 32)
                  ? buf[(size_t)cc * M_TOK + (n << 10) + (y << 5) + x] : 0.f;
    P[idx] = (short)f2b(v);
}

// ---------------------------------------------------------------------------
// bf16 MFMA GEMM: out[M x N] (+=) A[M x K(lda)] * W[N x K]^T
// 128x64 tile, 4 waves (2x2), BK=32, one 16x16x32 MFMA k-step per BK.
// TROUT: computes transposed product, writes out[n*M + m] (coalesced).
// AF32 : A is fp32, converted to bf16 during staging.
// ---------------------------------------------------------------------------
template <bool ADD, bool TROUT, bool OUTBF16, bool AF32>
__global__ __launch_bounds__(256) void mm_k(const void* __restrict__ Avp,
                                            const short* __restrict__ W,
                                            void* __restrict__ outp,
                                            int M, int N, int K, int lda) {
    __shared__ __align__(16) short As[128 * 40];
    __shared__ __align__(16) short Bs[64 * 40];
    const int tid = threadIdx.x;
    const int bm = blockIdx.x * 128;
    const int bn = blockIdx.y * 64;
    const int w = tid >> 6, lane = tid & 63;
    const int h = lane >> 4, l15 = lane & 15;
    const int wm = (w >> 1) * 64, wn = (w & 1) * 32;

    f32x4 acc[4][2];
#pragma unroll
    for (int i = 0; i < 4; ++i)
#pragma unroll
        for (int j = 0; j < 2; ++j) acc[i][j] = (f32x4){0.f, 0.f, 0.f, 0.f};

    for (int k0 = 0; k0 < K; k0 += 32) {
        // stage A: 128 rows x 32 k (512 chunks of 8 bf16)
#pragma unroll
        for (int e = 0; e < 2; ++e) {
            int li = tid + e * 256;
            int row = li >> 2, c4 = li & 3;
            int gk = k0 + c4 * 8;
            size_t abase = (size_t)(bm + row) * lda + gk;
            short tmp[8];
            if (AF32) {
                const float* ap = (const float*)Avp + abase;
                if (gk + 8 <= K) {
                    float4 va = *(const float4*)ap;
                    float4 vb = *(const float4*)(ap + 4);
                    tmp[0] = (short)f2b(va.x); tmp[1] = (short)f2b(va.y);
                    tmp[2] = (short)f2b(va.z); tmp[3] = (short)f2b(va.w);
                    tmp[4] = (short)f2b(vb.x); tmp[5] = (short)f2b(vb.y);
                    tmp[6] = (short)f2b(vb.z); tmp[7] = (short)f2b(vb.w);
                } else {
#pragma unroll
                    for (int i = 0; i < 8; ++i) tmp[i] = (gk + i < K) ? (short)f2b(ap[i]) : (short)0;
                }
            } else {
                const short* ap = (const short*)Avp + abase;
                if (gk + 8 <= K) {
                    i32x2 a = *(const i32x2*)ap;
                    i32x2 b = *(const i32x2*)(ap + 4);
                    *(i32x2*)&tmp[0] = a; *(i32x2*)&tmp[4] = b;
                } else {
#pragma unroll
                    for (int i = 0; i < 8; ++i) tmp[i] = (gk + i < K) ? ap[i] : (short)0;
                }
            }
            *(i32x4*)&As[row * 40 + c4 * 8] = *(i32x4*)tmp;
        }
        // stage W: 64 rows x 32 k
        {
            int row = tid >> 2, c4 = tid & 3;
            int gk = k0 + c4 * 8;
            int gn = bn + row;
            short tmp[8];
            if (gn < N && gk + 8 <= K) {
                const short* wp = W + (size_t)gn * K + gk;
                i32x2 a = *(const i32x2*)wp;
                i32x2 b = *(const i32x2*)(wp + 4);
                *(i32x2*)&tmp[0] = a; *(i32x2*)&tmp[4] = b;
            } else {
#pragma unroll
                for (int i = 0; i < 8; ++i)
                    tmp[i] = (gn < N && gk + i < K) ? W[(size_t)gn * K + gk + i] : (short)0;
            }
            *(i32x4*)&Bs[row * 40 + c4 * 8] = *(i32x4*)tmp;
        }
        __syncthreads();
        bf16x8 af[4], bf[2];
#pragma unroll
        for (int mi = 0; mi < 4; ++mi) af[mi] = *(const bf16x8*)&As[(wm + mi * 16 + l15) * 40 + h * 8];
#pragma unroll
        for (int nj = 0; nj < 2; ++nj) bf[nj] = *(const bf16x8*)&Bs[(wn + nj * 16 + l15) * 40 + h * 8];
#pragma unroll
        for (int mi = 0; mi < 4; ++mi)
#pragma unroll
            for (int nj = 0; nj < 2; ++nj) {
                if (TROUT)
                    acc[mi][nj] = __builtin_amdgcn_mfma_f32_16x16x32_bf16(bf[nj], af[mi], acc[mi][nj], 0, 0, 0);
                else
                    acc[mi][nj] = __builtin_amdgcn_mfma_f32_16x16x32_bf16(af[mi], bf[nj], acc[mi][nj], 0, 0, 0);
            }
        __syncthreads();
    }

    if (!TROUT) {
#pragma unroll
        for (int mi = 0; mi < 4; ++mi) {
#pragma unroll
            for (int nj = 0; nj < 2; ++nj) {
                int gn = bn + wn + nj * 16 + l15;
                if (gn < N) {
#pragma unroll
                    for (int r = 0; r < 4; ++r) {
                        int gm = bm + wm + mi * 16 + h * 4 + r;
                        float v = acc[mi][nj][r];
                        size_t oi = (size_t)gm * N + gn;
                        if (OUTBF16)      ((short*)outp)[oi] = (short)f2b(v);
                        else if (ADD)     ((float*)outp)[oi] += v;
                        else              ((float*)outp)[oi] = v;
                    }
                }
            }
        }
    } else {
#pragma unroll
        for (int mi = 0; mi < 4; ++mi) {
            int gm = bm + wm + mi * 16 + l15;
#pragma unroll
            for (int nj = 0; nj < 2; ++nj)
#pragma unroll
                for (int r = 0; r < 4; ++r) {
                    int gn = bn + wn + nj * 16 + h * 4 + r;
                    if (gn < N) ((float*)outp)[(size_t)gn * M + gm] = acc[mi][nj][r];
                }
        }
    }
}

// ---------------------------------------------------------------------------
// LayerNorm D=128, fp32 in -> bf16 out. 4 tokens/block, 1 wave/token.
// ---------------------------------------------------------------------------
__global__ __launch_bounds__(256) void ln_k(const float* __restrict__ in,
                                            const float* __restrict__ w,
                                            const float* __restrict__ b,
                                            short* __restrict__ out) {
    int t = blockIdx.x * 4 + (threadIdx.x >> 6);
    int lane = threadIdx.x & 63;
    float2 v = *(const float2*)(in + (size_t)t * 128 + lane * 2);
    float s = v.x + v.y, sq = v.x * v.x + v.y * v.y;
#pragma unroll
    for (int off = 32; off > 0; off >>= 1) { s += __shfl_xor(s, off); sq += __shfl_xor(sq, off); }
    float mean = s * (1.f / 128.f);
    float var = sq * (1.f / 128.f) - mean * mean;
    float rstd = rsqrtf(var + 1e-5f);
    float2 wv = *(const float2*)(w + lane * 2);
    float2 bv = *(const float2*)(b + lane * 2);
    float ox = (v.x - mean) * rstd * wv.x + bv.x;
    float oy = (v.y - mean) * rstd * wv.y + bv.y;
    ((unsigned*)out)[(size_t)t * 64 + lane] = f2b(ox) | ((unsigned)f2b(oy) << 16);
}

// ---------------------------------------------------------------------------
// Depthwise 3x3 (zero pad), bf16 in [t][384] -> fp32 out [t][384], 2 ch/thread
// ---------------------------------------------------------------------------
__global__ __launch_bounds__(256) void dw_k(const short* __restrict__ in,
                                            const float* __restrict__ w,
                                            float* __restrict__ out) {
    int idx = blockIdx.x * 256 + threadIdx.x;    // < M*192
    int ch2 = idx % 192;
    int t = idx / 192;
    int c0 = ch2 * 2;
    int l = t & 1023, nb = t >> 10;
    int y = l >> 5, x = l & 31;
    int tb = nb << 10;
    float a0 = 0.f, a1 = 0.f;
#pragma unroll
    for (int i = 0; i < 3; ++i) {
        int yy = y + i - 1; if (yy < 0 || yy >= 32) continue;
#pragma unroll
        for (int j = 0; j < 3; ++j) {
            int xx = x + j - 1; if (xx < 0 || xx >= 32) continue;
            unsigned u = *(const unsigned*)&in[(size_t)(tb + (yy << 5) + xx) * 384 + c0];
            a0 += b2f((unsigned short)(u & 0xffff)) * w[c0 * 9 + i * 3 + j];
            a1 += b2f((unsigned short)(u >> 16)) * w[(c0 + 1) * 9 + i * 3 + j];
        }
    }
    *(float2*)&out[(size_t)t * 384 + c0] = make_float2(a0, a1);
}

// ---------------------------------------------------------------------------
// l2norm q,k (groups 0..7) + convert v (8..11): fp32 [t][384] -> bf16 [t][384]
// ---------------------------------------------------------------------------
__global__ __launch_bounds__(256) void l2n_k(const float* __restrict__ in, short* __restrict__ out) {
    int idx = blockIdx.x * 256 + threadIdx.x;    // < M*12
    int g = idx % 12;
    int t = idx / 12;
    const float* p = in + (size_t)t * 384 + g * 32;
    float4 v[8]; float ss = 0.f;
#pragma unroll
    for (int c = 0; c < 8; ++c) {
        v[c] = *(const float4*)(p + c * 4);
        ss += v[c].x * v[c].x + v[c].y * v[c].y + v[c].z * v[c].z + v[c].w * v[c].w;
    }
    float sc = (g < 8) ? (1.f / fmaxf(sqrtf(ss), 1e-12f)) : 1.f;
    unsigned* o = (unsigned*)(out + (size_t)t * 384 + g * 32);
#pragma unroll
    for (int c = 0; c < 8; ++c) {
        o[c * 2]     = f2b(v[c].x * sc) | ((unsigned)f2b(v[c].y * sc) << 16);
        o[c * 2 + 1] = f2b(v[c].z * sc) | ((unsigned)f2b(v[c].w * sc) << 16);
    }
}

// ---------------------------------------------------------------------------
// MFMA flash attention. block = (n, head, 64 q-rows) as 4 waves x 16 rows.
// S^T = K.Q^T so softmax rows are lane-local; P rebuilt via shfl for PV.
// qkv bf16 [t][384]: q|k|v each 128 = 4 heads x 32. out bf16 [t][128].
// ---------------------------------------------------------------------------
__global__ __launch_bounds__(256) void attn_k(const short* __restrict__ qkv,
                                              const float* __restrict__ temp,
                                              short* __restrict__ outp) {
    __shared__ __align__(16) short Ks[32 * 40];
    __shared__ __align__(16) short Vt[32 * 40];
    const int bid = blockIdx.x;
    const int qt = bid & 15, nh = bid >> 4;
    const int hd = nh & 3, n = nh >> 2;
    const int tid = threadIdx.x;
    const int w = tid >> 6, lane = tid & 63;
    const int h = lane >> 4, l15 = lane & 15;
    const size_t base = (size_t)n * 1024 * 384;
    const int qrow = qt * 64 + w * 16 + l15;
    const float ts = temp[hd];

    bf16x8 qf = *(const bf16x8*)(qkv + base + (size_t)qrow * 384 + hd * 32 + h * 8);
    f32x4 o0 = {0.f, 0.f, 0.f, 0.f}, o1 = {0.f, 0.f, 0.f, 0.f};
    float m = -1e30f, lsum = 0.f;

    for (int j0 = 0; j0 < 1024; j0 += 32) {
        __syncthreads();
        if (tid < 128) {             // stage K tile [32 keys][32 c]
            int key = tid >> 2, c4 = tid & 3;
            i32x4 kv = *(const i32x4*)(qkv + base + (size_t)(j0 + key) * 384 + 128 + hd * 32 + c4 * 8);
            *(i32x4*)&Ks[key * 40 + c4 * 8] = kv;
        } else {                     // stage V transposed: Vt[c][key]
            int t2 = tid - 128;
            int key = t2 >> 2, c4 = t2 & 3;
            const short* vp = qkv + base + (size_t)(j0 + key) * 384 + 256 + hd * 32 + c4 * 8;
#pragma unroll
            for (int i = 0; i < 8; ++i) Vt[(c4 * 8 + i) * 40 + key] = vp[i];
        }
        __syncthreads();
        bf16x8 kf0 = *(const bf16x8*)&Ks[l15 * 40 + h * 8];
        bf16x8 kf1 = *(const bf16x8*)&Ks[(16 + l15) * 40 + h * 8];
        f32x4 z = {0.f, 0.f, 0.f, 0.f};
        f32x4 s0 = __builtin_amdgcn_mfma_f32_16x16x32_bf16(kf0, qf, z, 0, 0, 0);
        f32x4 s1 = __builtin_amdgcn_mfma_f32_16x16x32_bf16(kf1, qf, z, 0, 0, 0);
        // lane holds S^T[key][q]: q = l15, keys = j0 + {4h+r, 16+4h+r}
        float sv[8];
#pragma unroll
        for (int r = 0; r < 4; ++r) { sv[r] = s0[r] * ts; sv[4 + r] = s1[r] * ts; }
        float tm = sv[0];
#pragma unroll
        for (int r = 1; r < 8; ++r) tm = fmaxf(tm, sv[r]);
        tm = fmaxf(tm, __shfl_xor(tm, 16));
        tm = fmaxf(tm, __shfl_xor(tm, 32));
        float nm = fmaxf(m, tm);
        float rs = __expf(m - nm);
        float p[8]; float ps = 0.f;
#pragma unroll
        for (int r = 0; r < 8; ++r) { p[r] = __expf(sv[r] - nm); ps += p[r]; }
        ps += __shfl_xor(ps, 16);
        ps += __shfl_xor(ps, 32);
        lsum = lsum * rs + ps; m = nm;
#pragma unroll
        for (int r = 0; r < 4; ++r) { o0[r] *= rs; o1[r] *= rs; }
        // rebuild P as PV B-frag: lane needs keys 8h+0..7 (bf16 pairs)
        unsigned a01 = f2b(p[0]) | ((unsigned)f2b(p[1]) << 16);
        unsigned a23 = f2b(p[2]) | ((unsigned)f2b(p[3]) << 16);
        unsigned b01 = f2b(p[4]) | ((unsigned)f2b(p[5]) << 16);
        unsigned b23 = f2b(p[6]) | ((unsigned)f2b(p[7]) << 16);
        int src0 = ((2 * h) & 3) * 16 + l15;
        int src1 = src0 + 16;
        unsigned A0 = (unsigned)__shfl((int)a01, src0), A1 = (unsigned)__shfl((int)a23, src0);
        unsigned A2 = (unsigned)__shfl((int)a01, src1), A3 = (unsigned)__shfl((int)a23, src1);
        unsigned B0 = (unsigned)__shfl((int)b01, src0), B1 = (unsigned)__shfl((int)b23, src0);
        unsigned B2 = (unsigned)__shfl((int)b01, src1), B3 = (unsigned)__shfl((int)b23, src1);
        union { unsigned u[4]; bf16x8 v; } pf;
        bool lo = (h < 2);
        pf.u[0] = lo ? A0 : B0; pf.u[1] = lo ? A1 : B1;
        pf.u[2] = lo ? A2 : B2; pf.u[3] = lo ? A3 : B3;
        bf16x8 vf0 = *(const bf16x8*)&Vt[l15 * 40 + h * 8];
        bf16x8 vf1 = *(const bf16x8*)&Vt[(16 + l15) * 40 + h * 8];
        o0 = __builtin_amdgcn_mfma_f32_16x16x32_bf16(vf0, pf.v, o0, 0, 0, 0);
        o1 = __builtin_amdgcn_mfma_f32_16x16x32_bf16(vf1, pf.v, o1, 0, 0, 0);
    }
    float inv = 1.f / lsum;
    size_t ob = ((size_t)n * 1024 + qrow) * 128 + hd * 32;   // lane's q = l15 (in qrow)
    unsigned u;
    u = f2b(o0[0] * inv) | ((unsigned)f2b(o0[1] * inv) << 16); *(unsigned*)(outp + ob + h * 4) = u;
    u = f2b(o0[2] * inv) | ((unsigned)f2b(o0[3] * inv) << 16); *(unsigned*)(outp + ob + h * 4 + 2) = u;
    u = f2b(o1[0] * inv) | ((unsigned)f2b(o1[1] * inv) << 16); *(unsigned*)(outp + ob + 16 + h * 4) = u;
    u = f2b(o1[2] * inv) | ((unsigned)f2b(o1[3] * inv) << 16); *(unsigned*)(outp + ob + 16 + h * 4 + 2) = u;
}

// ---------------------------------------------------------------------------
// GDFN: dual depthwise 3x3 + exact gelu gate. bf16 in [t][680] -> bf16 [t][340]
// ---------------------------------------------------------------------------
__global__ __launch_bounds__(256) void gdfn_k(const short* __restrict__ in,
                                              const float* __restrict__ w,
                                              short* __restrict__ out) {
    int idx = blockIdx.x * 256 + threadIdx.x;    // < M*170
    int ch2 = idx % 170;
    int t = idx / 170;
    int c0 = ch2 * 2;
    int l = t & 1023, nb = t >> 10;
    int y = l >> 5, x = l & 31;
    int tb = nb << 10;
    float a0 = 0.f, a1 = 0.f, g0 = 0.f, g1 = 0.f;
#pragma unroll
    for (int i = 0; i < 3; ++i) {
        int yy = y + i - 1; if (yy < 0 || yy >= 32) continue;
#pragma unroll
        for (int j = 0; j < 3; ++j) {
            int xx = x + j - 1; if (xx < 0 || xx >= 32) continue;
            const short* pp = in + (size_t)(tb + (yy << 5) + xx) * 680;
            unsigned u  = *(const unsigned*)&pp[c0];
            unsigned ug = *(const unsigned*)&pp[c0 + 340];
            a0 += b2f((unsigned short)(u & 0xffff)) * w[c0 * 9 + i * 3 + j];
            a1 += b2f((unsigned short)(u >> 16)) * w[(c0 + 1) * 9 + i * 3 + j];
            g0 += b2f((unsigned short)(ug & 0xffff)) * w[(c0 + 340) * 9 + i * 3 + j];
            g1 += b2f((unsigned short)(ug >> 16)) * w[(c0 + 341) * 9 + i * 3 + j];
        }
    }
    float r0 = 0.5f * a0 * (1.f + erff(a0 * 0.70710678118f)) * g0;
    float r1 = 0.5f * a1 * (1.f + erff(a1 * 0.70710678118f)) * g1;
    *(unsigned*)&out[(size_t)t * 340 + c0] = f2b(r0) | ((unsigned)f2b(r1) << 16);
}

// ---------------------------------------------------------------------------
extern "C" void kernel_launch(void* const* d_in, const int* in_sizes, int n_in,
                              void* d_out, int out_size, void* d_ws, size_t ws_size,
                              hipStream_t stream) {
    const float* buffer      = (const float*)d_in[0];
    const float* mlp_w       = (const float*)d_in[1];
    const float* ln_attn_w   = (const float*)d_in[2];
    const float* ln_attn_b   = (const float*)d_in[3];
    const float* ln_ffn_w    = (const float*)d_in[4];
    const float* ln_ffn_b    = (const float*)d_in[5];
    const float* qkv_w       = (const float*)d_in[6];
    const float* qkv_dw_w    = (const float*)d_in[7];
    const float* temperature = (const float*)d_in[8];
    const float* proj_attn_w = (const float*)d_in[9];
    const float* ffn_in_w    = (const float*)d_in[10];
    const float* ffn_dw_w    = (const float*)d_in[11];
    const float* ffn_out_w   = (const float*)d_in[12];
    const float* proj3d_w    = (const float*)d_in[13];

    char* wsb = (char*)d_ws;
    // bf16 weights (278016 elems)
    short* Wbf     = (short*)wsb;
    short* mlpW    = Wbf;              // [128][576]
    short* qkvW    = Wbf + 73728;      // [384][128]
    short* projW   = Wbf + 122880;     // [128][128]
    short* ffnInW  = Wbf + 139264;     // [680][128]
    short* ffnOutW = Wbf + 226304;     // [128][340]
    short* p3dW    = Wbf + 269824;     // [64][128]
    // activations (byte offsets; B1 is a union: PatchB then QKVdw)
    short* PatchB = (short*)(wsb + 556032);      // [M][576] bf16 (29.5 MB)
    float* QKVdw  = (float*)(wsb + 556032);      // [M][384] f32  (39.3 MB, after S2T)
    float* tok    = (float*)(wsb + 39877632);    // [M][128] f32 residual stream
    short* LNbf   = (short*)(wsb + 52984832);    // [M][128] bf16
    short* QKVpre = (short*)(wsb + 59538432);    // [M][384] bf16
    short* qkvb   = (short*)(wsb + 79199232);    // [M][384] bf16 (post dw+l2n)
    short* AObf   = (short*)(wsb + 98860032);    // [M][128] bf16 attn out
    short* F1     = (short*)(wsb + 105413632);   // [M][680] bf16
    short* G      = (short*)(wsb + 140229632);   // [M][340] bf16

    dim3 blk(256);

    cvtw_k<<<1086, blk, 0, stream>>>(mlp_w, qkv_w, proj_attn_w, ffn_in_w, ffn_out_w, proj3d_w, Wbf);
    unfold_k<<<57600, blk, 0, stream>>>(buffer, PatchB);

    // S2T: tok = patches @ mlp_w^T (f32 out)
    mm_k<false, false, false, false><<<dim3(200, 2), blk, 0, stream>>>(PatchB, mlpW, tok, M_TOK, 128, 576, 576);
    ln_k<<<6400, blk, 0, stream>>>(tok, ln_attn_w, ln_attn_b, LNbf);
    // qkv 1x1 (bf16 out)
    mm_k<false, false, true, false><<<dim3(200, 6), blk, 0, stream>>>(LNbf, qkvW, QKVpre, M_TOK, 384, 128, 128);
    dw_k<<<19200, blk, 0, stream>>>(QKVpre, qkv_dw_w, QKVdw);
    l2n_k<<<1200, blk, 0, stream>>>(QKVdw, qkvb);
    attn_k<<<1600, blk, 0, stream>>>(qkvb, temperature, AObf);
    // proj + residual
    mm_k<true, false, false, false><<<dim3(200, 2), blk, 0, stream>>>(AObf, projW, tok, M_TOK, 128, 128, 128);
    ln_k<<<6400, blk, 0, stream>>>(tok, ln_ffn_w, ln_ffn_b, LNbf);
    // ffn_in 1x1 (bf16 out)
    mm_k<false, false, true, false><<<dim3(200, 11), blk, 0, stream>>>(LNbf, ffnInW, F1, M_TOK, 680, 128, 128);
    gdfn_k<<<17000, blk, 0, stream>>>(F1, ffn_dw_w, G);
    // ffn_out + residual
    mm_k<true, false, false, false><<<dim3(200, 2), blk, 0, stream>>>(G, ffnOutW, tok, M_TOK, 128, 340, 340);
    // Token2SAI: out[o][t] = tok @ proj3d^T (transposed product, coalesced)
    mm_k<false, true, false, true><<<dim3(200, 1), blk, 0, stream>>>(tok, p3dW, d_out, M_TOK, 64, 128, 128);
}

// Round 3
// 272.688 us; speedup vs baseline: 4.2376x; 1.6939x over previous
//
#include <hip/hip_runtime.h>
#include <math.h>

#define M_TOK 25600   // 25 images * 1024 tokens

typedef __attribute__((ext_vector_type(8))) short bf16x8;
typedef __attribute__((ext_vector_type(4))) float f32x4;
typedef __attribute__((ext_vector_type(4))) int   i32x4;
typedef __attribute__((ext_vector_type(2))) int   i32x2;

__device__ __forceinline__ unsigned short f2b(float x) {
    unsigned u = __builtin_bit_cast(unsigned, x);
    return (unsigned short)((u + 0x7fffu + ((u >> 16) & 1u)) >> 16);
}
__device__ __forceinline__ float b2f(unsigned short h) {
    unsigned u = ((unsigned)h) << 16;
    return __builtin_bit_cast(float, u);
}

// ---------------------------------------------------------------------------
// Weight fp32->bf16 conversion (6 matrices, concatenated destination)
// ---------------------------------------------------------------------------
__global__ __launch_bounds__(256) void cvtw_k(const float* __restrict__ s0, const float* __restrict__ s1,
                                              const float* __restrict__ s2, const float* __restrict__ s3,
                                              const float* __restrict__ s4, const float* __restrict__ s5,
                                              short* __restrict__ dst) {
    int i = blockIdx.x * 256 + threadIdx.x;      // < 278016
    const float* s; int off;
    if      (i < 73728)  { s = s0; off = i; }
    else if (i < 122880) { s = s1; off = i - 73728; }
    else if (i < 139264) { s = s2; off = i - 122880; }
    else if (i < 226304) { s = s3; off = i - 139264; }
    else if (i < 269824) { s = s4; off = i - 226304; }
    else                 { s = s5; off = i - 269824; }
    dst[i] = (short)f2b(s[off]);
}

// ---------------------------------------------------------------------------
// Depthwise-weight transpose: [C][9] -> [9][C] (f32), qkv (384) + ffn (680)
// ---------------------------------------------------------------------------
__global__ __launch_bounds__(256) void twp_k(const float* __restrict__ qw,
                                             const float* __restrict__ fw,
                                             float* __restrict__ wqT,
                                             float* __restrict__ wgT) {
    int i = blockIdx.x * 256 + threadIdx.x;      // < 9576
    if (i < 3456) {
        int tap = i / 384, c = i % 384;
        wqT[i] = qw[c * 9 + tap];
    } else if (i < 9576) {
        int j = i - 3456;
        int tap = j / 680, c = j % 680;
        wgT[j] = fw[c * 9 + tap];
    }
}

// ---------------------------------------------------------------------------
// im2col 3x3 (zero pad) -> bf16 patch matrix [M][576], k = cc*9 + (i*3+j)
// ---------------------------------------------------------------------------
__global__ __launch_bounds__(256) void unfold_k(const float* __restrict__ buf, short* __restrict__ P) {
    int idx = blockIdx.x * 256 + threadIdx.x;    // < M*576
    int kk = idx % 576;
    int t  = idx / 576;
    int cc = kk / 9, tap = kk - cc * 9;
    int ti = tap / 3, tj = tap - ti * 3;
    int l = t & 1023, n = t >> 10;
    int y = (l >> 5) + ti - 1, x = (l & 31) + tj - 1;
    float v = (y >= 0 && y < 32 && x >= 0 && x < 32)
                  ? buf[(size_t)cc * M_TOK + (n << 10) + (y << 5) + x] : 0.f;
    P[idx] = (short)f2b(v);
}

// ---------------------------------------------------------------------------
// bf16 MFMA GEMM: out[M x N] (+=) A[M x K(lda)] * W[N x K]^T
// 128x64 tile, 4 waves (2x2), BK=32.
// ---------------------------------------------------------------------------
template <bool ADD, bool TROUT, bool OUTBF16, bool AF32>
__global__ __launch_bounds__(256) void mm_k(const void* __restrict__ Avp,
                                            const short* __restrict__ W,
                                            void* __restrict__ outp,
                                            int M, int N, int K, int lda) {
    __shared__ __align__(16) short As[128 * 40];
    __shared__ __align__(16) short Bs[64 * 40];
    const int tid = threadIdx.x;
    const int bm = blockIdx.x * 128;
    const int bn = blockIdx.y * 64;
    const int w = tid >> 6, lane = tid & 63;
    const int h = lane >> 4, l15 = lane & 15;
    const int wm = (w >> 1) * 64, wn = (w & 1) * 32;

    f32x4 acc[4][2];
#pragma unroll
    for (int i = 0; i < 4; ++i)
#pragma unroll
        for (int j = 0; j < 2; ++j) acc[i][j] = (f32x4){0.f, 0.f, 0.f, 0.f};

    for (int k0 = 0; k0 < K; k0 += 32) {
#pragma unroll
        for (int e = 0; e < 2; ++e) {
            int li = tid + e * 256;
            int row = li >> 2, c4 = li & 3;
            int gk = k0 + c4 * 8;
            size_t abase = (size_t)(bm + row) * lda + gk;
            short tmp[8];
            if (AF32) {
                const float* ap = (const float*)Avp + abase;
                if (gk + 8 <= K) {
                    float4 va = *(const float4*)ap;
                    float4 vb = *(const float4*)(ap + 4);
                    tmp[0] = (short)f2b(va.x); tmp[1] = (short)f2b(va.y);
                    tmp[2] = (short)f2b(va.z); tmp[3] = (short)f2b(va.w);
                    tmp[4] = (short)f2b(vb.x); tmp[5] = (short)f2b(vb.y);
                    tmp[6] = (short)f2b(vb.z); tmp[7] = (short)f2b(vb.w);
                } else {
#pragma unroll
                    for (int i = 0; i < 8; ++i) tmp[i] = (gk + i < K) ? (short)f2b(ap[i]) : (short)0;
                }
            } else {
                const short* ap = (const short*)Avp + abase;
                if (gk + 8 <= K) {
                    i32x2 a = *(const i32x2*)ap;
                    i32x2 b = *(const i32x2*)(ap + 4);
                    *(i32x2*)&tmp[0] = a; *(i32x2*)&tmp[4] = b;
                } else {
#pragma unroll
                    for (int i = 0; i < 8; ++i) tmp[i] = (gk + i < K) ? ap[i] : (short)0;
                }
            }
            *(i32x4*)&As[row * 40 + c4 * 8] = *(i32x4*)tmp;
        }
        {
            int row = tid >> 2, c4 = tid & 3;
            int gk = k0 + c4 * 8;
            int gn = bn + row;
            short tmp[8];
            if (gn < N && gk + 8 <= K) {
                const short* wp = W + (size_t)gn * K + gk;
                i32x2 a = *(const i32x2*)wp;
                i32x2 b = *(const i32x2*)(wp + 4);
                *(i32x2*)&tmp[0] = a; *(i32x2*)&tmp[4] = b;
            } else {
#pragma unroll
                for (int i = 0; i < 8; ++i)
                    tmp[i] = (gn < N && gk + i < K) ? W[(size_t)gn * K + gk + i] : (short)0;
            }
            *(i32x4*)&Bs[row * 40 + c4 * 8] = *(i32x4*)tmp;
        }
        __syncthreads();
        bf16x8 af[4], bf[2];
#pragma unroll
        for (int mi = 0; mi < 4; ++mi) af[mi] = *(const bf16x8*)&As[(wm + mi * 16 + l15) * 40 + h * 8];
#pragma unroll
        for (int nj = 0; nj < 2; ++nj) bf[nj] = *(const bf16x8*)&Bs[(wn + nj * 16 + l15) * 40 + h * 8];
#pragma unroll
        for (int mi = 0; mi < 4; ++mi)
#pragma unroll
            for (int nj = 0; nj < 2; ++nj) {
                if (TROUT)
                    acc[mi][nj] = __builtin_amdgcn_mfma_f32_16x16x32_bf16(bf[nj], af[mi], acc[mi][nj], 0, 0, 0);
                else
                    acc[mi][nj] = __builtin_amdgcn_mfma_f32_16x16x32_bf16(af[mi], bf[nj], acc[mi][nj], 0, 0, 0);
            }
        __syncthreads();
    }

    if (!TROUT) {
#pragma unroll
        for (int mi = 0; mi < 4; ++mi) {
#pragma unroll
            for (int nj = 0; nj < 2; ++nj) {
                int gn = bn + wn + nj * 16 + l15;
                if (gn < N) {
#pragma unroll
                    for (int r = 0; r < 4; ++r) {
                        int gm = bm + wm + mi * 16 + h * 4 + r;
                        float v = acc[mi][nj][r];
                        size_t oi = (size_t)gm * N + gn;
                        if (OUTBF16)      ((short*)outp)[oi] = (short)f2b(v);
                        else if (ADD)     ((float*)outp)[oi] += v;
                        else              ((float*)outp)[oi] = v;
                    }
                }
            }
        }
    } else {
#pragma unroll
        for (int mi = 0; mi < 4; ++mi) {
            int gm = bm + wm + mi * 16 + l15;
#pragma unroll
            for (int nj = 0; nj < 2; ++nj)
#pragma unroll
                for (int r = 0; r < 4; ++r) {
                    int gn = bn + wn + nj * 16 + h * 4 + r;
                    if (gn < N) ((float*)outp)[(size_t)gn * M + gm] = acc[mi][nj][r];
                }
        }
    }
}

// ---------------------------------------------------------------------------
// LayerNorm D=128, fp32 in -> bf16 out.
// ---------------------------------------------------------------------------
__global__ __launch_bounds__(256) void ln_k(const float* __restrict__ in,
                                            const float* __restrict__ w,
                                            const float* __restrict__ b,
                                            short* __restrict__ out) {
    int t = blockIdx.x * 4 + (threadIdx.x >> 6);
    int lane = threadIdx.x & 63;
    float2 v = *(const float2*)(in + (size_t)t * 128 + lane * 2);
    float s = v.x + v.y, sq = v.x * v.x + v.y * v.y;
#pragma unroll
    for (int off = 32; off > 0; off >>= 1) { s += __shfl_xor(s, off); sq += __shfl_xor(sq, off); }
    float mean = s * (1.f / 128.f);
    float var = sq * (1.f / 128.f) - mean * mean;
    float rstd = rsqrtf(var + 1e-5f);
    float2 wv = *(const float2*)(w + lane * 2);
    float2 bv = *(const float2*)(b + lane * 2);
    float ox = (v.x - mean) * rstd * wv.x + bv.x;
    float oy = (v.y - mean) * rstd * wv.y + bv.y;
    ((unsigned*)out)[(size_t)t * 64 + lane] = f2b(ox) | ((unsigned)f2b(oy) << 16);
}

// ---------------------------------------------------------------------------
// Fused qkv depthwise 3x3 + l2norm(q,k heads). thread = (token, 8-ch chunk).
// in QKVpre bf16 [M][384], wqT f32 [9][384], out qkvb bf16 [M][384].
// A 32-ch head = 4 adjacent lanes -> shfl_xor(1,2) for the norm reduction.
// ---------------------------------------------------------------------------
__global__ __launch_bounds__(256) void dwl2n_k(const short* __restrict__ in,
                                               const float* __restrict__ wqT,
                                               short* __restrict__ out) {
    int idx = blockIdx.x * 256 + threadIdx.x;    // < M*48
    int q = idx % 48;
    int t = idx / 48;
    int c0 = q * 8;
    int l = t & 1023, n = t >> 10;
    int y = l >> 5, x = l & 31;
    int tb = n << 10;

    float acc[8];
#pragma unroll
    for (int k = 0; k < 8; ++k) acc[k] = 0.f;

#pragma unroll
    for (int i = 0; i < 3; ++i) {
        int yy = y + i - 1;
        if (yy < 0 || yy >= 32) continue;
#pragma unroll
        for (int j = 0; j < 3; ++j) {
            int xx = x + j - 1;
            if (xx < 0 || xx >= 32) continue;
            bf16x8 d = *(const bf16x8*)(in + (size_t)(tb + (yy << 5) + xx) * 384 + c0);
            float4 wa = *(const float4*)(wqT + (i * 3 + j) * 384 + c0);
            float4 wb = *(const float4*)(wqT + (i * 3 + j) * 384 + c0 + 4);
            acc[0] += b2f((unsigned short)d[0]) * wa.x;
            acc[1] += b2f((unsigned short)d[1]) * wa.y;
            acc[2] += b2f((unsigned short)d[2]) * wa.z;
            acc[3] += b2f((unsigned short)d[3]) * wa.w;
            acc[4] += b2f((unsigned short)d[4]) * wb.x;
            acc[5] += b2f((unsigned short)d[5]) * wb.y;
            acc[6] += b2f((unsigned short)d[6]) * wb.z;
            acc[7] += b2f((unsigned short)d[7]) * wb.w;
        }
    }
    float ss = 0.f;
#pragma unroll
    for (int k = 0; k < 8; ++k) ss += acc[k] * acc[k];
    ss += __shfl_xor(ss, 1);
    ss += __shfl_xor(ss, 2);
    float sc = (c0 < 256) ? (1.f / fmaxf(sqrtf(ss), 1e-12f)) : 1.f;
    unsigned o[4];
#pragma unroll
    for (int k = 0; k < 4; ++k)
        o[k] = f2b(acc[2 * k] * sc) | ((unsigned)f2b(acc[2 * k + 1] * sc) << 16);
    *(i32x4*)(out + (size_t)t * 384 + c0) = *(i32x4*)o;
}

// ---------------------------------------------------------------------------
// Fused GDFN depthwise: dual 3x3 dwconv + exact gelu gate.
// thread = (token, 8-ch chunk of 344-padded). in F1 bf16 [M][680],
// wgT f32 [9][680], out G bf16 [M][344] (cols >=340 unwritten).
// ---------------------------------------------------------------------------
__global__ __launch_bounds__(256) void gdfn2_k(const short* __restrict__ in,
                                               const float* __restrict__ wgT,
                                               short* __restrict__ out) {
    int idx = blockIdx.x * 256 + threadIdx.x;    // < M*43
    int q = idx % 43;
    int t = idx / 43;
    int c0 = q * 8;
    int l = t & 1023, n = t >> 10;
    int y = l >> 5, x = l & 31;
    int tb = n << 10;

    float a[8], g[8];
#pragma unroll
    for (int k = 0; k < 8; ++k) { a[k] = 0.f; g[k] = 0.f; }

#pragma unroll
    for (int i = 0; i < 3; ++i) {
        int yy = y + i - 1;
        if (yy < 0 || yy >= 32) continue;
#pragma unroll
        for (int j = 0; j < 3; ++j) {
            int xx = x + j - 1;
            if (xx < 0 || xx >= 32) continue;
            const short* p = in + (size_t)(tb + (yy << 5) + xx) * 680 + c0;
            bf16x8 d1 = *(const bf16x8*)p;          // 16B aligned
            i32x2 d2a = *(const i32x2*)(p + 340);   // 8B aligned
            i32x2 d2b = *(const i32x2*)(p + 344);
            short d2[8];
            *(i32x2*)&d2[0] = d2a; *(i32x2*)&d2[4] = d2b;
            const float* wp = wgT + (i * 3 + j) * 680 + c0;
            float4 w1a = *(const float4*)wp;
            float4 w1b = *(const float4*)(wp + 4);
            float w1[8] = {w1a.x, w1a.y, w1a.z, w1a.w, w1b.x, w1b.y, w1b.z, w1b.w};
            float w2[8];
#pragma unroll
            for (int k = 0; k < 8; ++k) w2[k] = wp[340 + k];
#pragma unroll
            for (int k = 0; k < 8; ++k) {
                a[k] += b2f((unsigned short)d1[k]) * w1[k];
                g[k] += b2f((unsigned short)d2[k]) * w2[k];
            }
        }
    }
    unsigned o[4];
#pragma unroll
    for (int k = 0; k < 4; ++k) {
        float r0 = 0.5f * a[2 * k] * (1.f + erff(a[2 * k] * 0.70710678118f)) * g[2 * k];
        float r1 = 0.5f * a[2 * k + 1] * (1.f + erff(a[2 * k + 1] * 0.70710678118f)) * g[2 * k + 1];
        o[k] = f2b(r0) | ((unsigned)f2b(r1) << 16);
    }
    short* op = out + (size_t)t * 344 + c0;
    if (q < 42) *(i32x4*)op = *(i32x4*)o;
    else        *(i32x2*)op = (i32x2){(int)o[0], (int)o[1]};   // ch 336..339
}

// ---------------------------------------------------------------------------
// MFMA flash attention (unchanged from round 2).
// ---------------------------------------------------------------------------
__global__ __launch_bounds__(256) void attn_k(const short* __restrict__ qkv,
                                              const float* __restrict__ temp,
                                              short* __restrict__ outp) {
    __shared__ __align__(16) short Ks[32 * 40];
    __shared__ __align__(16) short Vt[32 * 40];
    const int bid = blockIdx.x;
    const int qt = bid & 15, nh = bid >> 4;
    const int hd = nh & 3, n = nh >> 2;
    const int tid = threadIdx.x;
    const int w = tid >> 6, lane = tid & 63;
    const int h = lane >> 4, l15 = lane & 15;
    const size_t base = (size_t)n * 1024 * 384;
    const int qrow = qt * 64 + w * 16 + l15;
    const float ts = temp[hd];

    bf16x8 qf = *(const bf16x8*)(qkv + base + (size_t)qrow * 384 + hd * 32 + h * 8);
    f32x4 o0 = {0.f, 0.f, 0.f, 0.f}, o1 = {0.f, 0.f, 0.f, 0.f};
    float m = -1e30f, lsum = 0.f;

    for (int j0 = 0; j0 < 1024; j0 += 32) {
        __syncthreads();
        if (tid < 128) {
            int key = tid >> 2, c4 = tid & 3;
            i32x4 kv = *(const i32x4*)(qkv + base + (size_t)(j0 + key) * 384 + 128 + hd * 32 + c4 * 8);
            *(i32x4*)&Ks[key * 40 + c4 * 8] = kv;
        } else {
            int t2 = tid - 128;
            int key = t2 >> 2, c4 = t2 & 3;
            const short* vp = qkv + base + (size_t)(j0 + key) * 384 + 256 + hd * 32 + c4 * 8;
#pragma unroll
            for (int i = 0; i < 8; ++i) Vt[(c4 * 8 + i) * 40 + key] = vp[i];
        }
        __syncthreads();
        bf16x8 kf0 = *(const bf16x8*)&Ks[l15 * 40 + h * 8];
        bf16x8 kf1 = *(const bf16x8*)&Ks[(16 + l15) * 40 + h * 8];
        f32x4 z = {0.f, 0.f, 0.f, 0.f};
        f32x4 s0 = __builtin_amdgcn_mfma_f32_16x16x32_bf16(kf0, qf, z, 0, 0, 0);
        f32x4 s1 = __builtin_amdgcn_mfma_f32_16x16x32_bf16(kf1, qf, z, 0, 0, 0);
        float sv[8];
#pragma unroll
        for (int r = 0; r < 4; ++r) { sv[r] = s0[r] * ts; sv[4 + r] = s1[r] * ts; }
        float tm = sv[0];
#pragma unroll
        for (int r = 1; r < 8; ++r) tm = fmaxf(tm, sv[r]);
        tm = fmaxf(tm, __shfl_xor(tm, 16));
        tm = fmaxf(tm, __shfl_xor(tm, 32));
        float nm = fmaxf(m, tm);
        float rs = __expf(m - nm);
        float p[8]; float ps = 0.f;
#pragma unroll
        for (int r = 0; r < 8; ++r) { p[r] = __expf(sv[r] - nm); ps += p[r]; }
        ps += __shfl_xor(ps, 16);
        ps += __shfl_xor(ps, 32);
        lsum = lsum * rs + ps; m = nm;
#pragma unroll
        for (int r = 0; r < 4; ++r) { o0[r] *= rs; o1[r] *= rs; }
        unsigned a01 = f2b(p[0]) | ((unsigned)f2b(p[1]) << 16);
        unsigned a23 = f2b(p[2]) | ((unsigned)f2b(p[3]) << 16);
        unsigned b01 = f2b(p[4]) | ((unsigned)f2b(p[5]) << 16);
        unsigned b23 = f2b(p[6]) | ((unsigned)f2b(p[7]) << 16);
        int src0 = ((2 * h) & 3) * 16 + l15;
        int src1 = src0 + 16;
        unsigned A0 = (unsigned)__shfl((int)a01, src0), A1 = (unsigned)__shfl((int)a23, src0);
        unsigned A2 = (unsigned)__shfl((int)a01, src1), A3 = (unsigned)__shfl((int)a23, src1);
        unsigned B0 = (unsigned)__shfl((int)b01, src0), B1 = (unsigned)__shfl((int)b23, src0);
        unsigned B2 = (unsigned)__shfl((int)b01, src1), B3 = (unsigned)__shfl((int)b23, src1);
        union { unsigned u[4]; bf16x8 v; } pf;
        bool lo = (h < 2);
        pf.u[0] = lo ? A0 : B0; pf.u[1] = lo ? A1 : B1;
        pf.u[2] = lo ? A2 : B2; pf.u[3] = lo ? A3 : B3;
        bf16x8 vf0 = *(const bf16x8*)&Vt[l15 * 40 + h * 8];
        bf16x8 vf1 = *(const bf16x8*)&Vt[(16 + l15) * 40 + h * 8];
        o0 = __builtin_amdgcn_mfma_f32_16x16x32_bf16(vf0, pf.v, o0, 0, 0, 0);
        o1 = __builtin_amdgcn_mfma_f32_16x16x32_bf16(vf1, pf.v, o1, 0, 0, 0);
    }
    float inv = 1.f / lsum;
    size_t ob = ((size_t)n * 1024 + qrow) * 128 + hd * 32;
    unsigned u;
    u = f2b(o0[0] * inv) | ((unsigned)f2b(o0[1] * inv) << 16); *(unsigned*)(outp + ob + h * 4) = u;
    u = f2b(o0[2] * inv) | ((unsigned)f2b(o0[3] * inv) << 16); *(unsigned*)(outp + ob + h * 4 + 2) = u;
    u = f2b(o1[0] * inv) | ((unsigned)f2b(o1[1] * inv) << 16); *(unsigned*)(outp + ob + 16 + h * 4) = u;
    u = f2b(o1[2] * inv) | ((unsigned)f2b(o1[3] * inv) << 16); *(unsigned*)(outp + ob + 16 + h * 4 + 2) = u;
}

// ---------------------------------------------------------------------------
extern "C" void kernel_launch(void* const* d_in, const int* in_sizes, int n_in,
                              void* d_out, int out_size, void* d_ws, size_t ws_size,
                              hipStream_t stream) {
    const float* buffer      = (const float*)d_in[0];
    const float* mlp_w       = (const float*)d_in[1];
    const float* ln_attn_w   = (const float*)d_in[2];
    const float* ln_attn_b   = (const float*)d_in[3];
    const float* ln_ffn_w    = (const float*)d_in[4];
    const float* ln_ffn_b    = (const float*)d_in[5];
    const float* qkv_w       = (const float*)d_in[6];
    const float* qkv_dw_w    = (const float*)d_in[7];
    const float* temperature = (const float*)d_in[8];
    const float* proj_attn_w = (const float*)d_in[9];
    const float* ffn_in_w    = (const float*)d_in[10];
    const float* ffn_dw_w    = (const float*)d_in[11];
    const float* ffn_out_w   = (const float*)d_in[12];
    const float* proj3d_w    = (const float*)d_in[13];

    char* wsb = (char*)d_ws;
    short* Wbf     = (short*)wsb;                 // 278016 bf16 weights
    short* mlpW    = Wbf;                         // [128][576]
    short* qkvW    = Wbf + 73728;                 // [384][128]
    short* projW   = Wbf + 122880;                // [128][128]
    short* ffnInW  = Wbf + 139264;                // [680][128]
    short* ffnOutW = Wbf + 226304;                // [128][340]
    short* p3dW    = Wbf + 269824;                // [64][128]
    float* wqT     = (float*)(wsb + 556032);      // [9][384] f32
    float* wgT     = (float*)(wsb + 569856);      // [9][680] f32
    short* PatchB  = (short*)(wsb + 594432);      // [M][576] bf16
    float* tok     = (float*)(wsb + 30085632);    // [M][128] f32
    short* LNbf    = (short*)(wsb + 43192832);    // [M][128] bf16
    short* QKVpre  = (short*)(wsb + 49746432);    // [M][384] bf16
    short* qkvb    = (short*)(wsb + 69407232);    // [M][384] bf16
    short* AObf    = (short*)(wsb + 89068032);    // [M][128] bf16
    short* F1      = (short*)(wsb + 95621632);    // [M][680] bf16
    short* G       = (short*)(wsb + 130437632);   // [M][344] bf16 (lda 344)

    dim3 blk(256);

    cvtw_k<<<1086, blk, 0, stream>>>(mlp_w, qkv_w, proj_attn_w, ffn_in_w, ffn_out_w, proj3d_w, Wbf);
    twp_k<<<38, blk, 0, stream>>>(qkv_dw_w, ffn_dw_w, wqT, wgT);
    unfold_k<<<57600, blk, 0, stream>>>(buffer, PatchB);

    // S2T: tok = patches @ mlp_w^T (f32 out)
    mm_k<false, false, false, false><<<dim3(200, 2), blk, 0, stream>>>(PatchB, mlpW, tok, M_TOK, 128, 576, 576);
    ln_k<<<6400, blk, 0, stream>>>(tok, ln_attn_w, ln_attn_b, LNbf);
    // qkv 1x1 (bf16 out)
    mm_k<false, false, true, false><<<dim3(200, 6), blk, 0, stream>>>(LNbf, qkvW, QKVpre, M_TOK, 384, 128, 128);
    // fused dwconv + l2norm
    dwl2n_k<<<4800, blk, 0, stream>>>(QKVpre, wqT, qkvb);
    attn_k<<<1600, blk, 0, stream>>>(qkvb, temperature, AObf);
    // proj + residual
    mm_k<true, false, false, false><<<dim3(200, 2), blk, 0, stream>>>(AObf, projW, tok, M_TOK, 128, 128, 128);
    ln_k<<<6400, blk, 0, stream>>>(tok, ln_ffn_w, ln_ffn_b, LNbf);
    // ffn_in 1x1 (bf16 out)
    mm_k<false, false, true, false><<<dim3(200, 11), blk, 0, stream>>>(LNbf, ffnInW, F1, M_TOK, 680, 128, 128);
    // fused GDFN dwconv + gelu gate
    gdfn2_k<<<4300, blk, 0, stream>>>(F1, wgT, G);
    // ffn_out + residual (A lda = 344)
    mm_k<true, false, false, false><<<dim3(200, 2), blk, 0, stream>>>(G, ffnOutW, tok, M_TOK, 128, 340, 344);
    // Token2SAI (transposed product, coalesced)
    mm_k<false, true, false, true><<<dim3(200, 1), blk, 0, stream>>>(tok, p3dW, d_out, M_TOK, 64, 128, 128);
}

// Round 4
// 252.836 us; speedup vs baseline: 4.5704x; 1.0785x over previous
//
#include <hip/hip_runtime.h>
#include <math.h>

#define M_TOK 25600   // 25 images * 1024 tokens

typedef __attribute__((ext_vector_type(8))) short bf16x8;
typedef __attribute__((ext_vector_type(4))) float f32x4;
typedef __attribute__((ext_vector_type(4))) int   i32x4;
typedef __attribute__((ext_vector_type(2))) int   i32x2;

__device__ __forceinline__ unsigned short f2b(float x) {
    unsigned u = __builtin_bit_cast(unsigned, x);
    return (unsigned short)((u + 0x7fffu + ((u >> 16) & 1u)) >> 16);
}
__device__ __forceinline__ float b2f(unsigned short h) {
    unsigned u = ((unsigned)h) << 16;
    return __builtin_bit_cast(float, u);
}
__device__ __forceinline__ unsigned cvtpk(float lo, float hi) {
    unsigned r;
    asm("v_cvt_pk_bf16_f32 %0, %1, %2" : "=v"(r) : "v"(lo), "v"(hi));
    return r;
}

// ---------------------------------------------------------------------------
// Weight fp32->bf16 conversion. mlp_w is re-laid-out [128][64][10] (tap 9 = 0)
// so the im2col patch matrix can use K=640 with 20B-aligned rows.
// ---------------------------------------------------------------------------
__global__ __launch_bounds__(256) void cvtw_k(const float* __restrict__ s0, const float* __restrict__ s1,
                                              const float* __restrict__ s2, const float* __restrict__ s3,
                                              const float* __restrict__ s4, const float* __restrict__ s5,
                                              short* __restrict__ dst) {
    int i = blockIdx.x * 256 + threadIdx.x;      // < 286208
    if (i < 81920) {
        int tap = i % 10, q = i / 10;            // q = d*64 + cc
        dst[i] = (tap < 9) ? (short)f2b(s0[q * 9 + tap]) : (short)0;
        return;
    }
    const float* s; int off;
    if      (i < 131072) { s = s1; off = i - 81920; }
    else if (i < 147456) { s = s2; off = i - 131072; }
    else if (i < 234496) { s = s3; off = i - 147456; }
    else if (i < 278016) { s = s4; off = i - 234496; }
    else                 { s = s5; off = i - 278016; }
    dst[i] = (short)f2b(s[off]);
}

// ---------------------------------------------------------------------------
// Depthwise-weight transpose: [C][9] -> [9][C] (f32), qkv (384) + ffn (680)
// ---------------------------------------------------------------------------
__global__ __launch_bounds__(256) void twp_k(const float* __restrict__ qw,
                                             const float* __restrict__ fw,
                                             float* __restrict__ wqT,
                                             float* __restrict__ wgT) {
    int i = blockIdx.x * 256 + threadIdx.x;      // < 9576
    if (i < 3456) {
        int tap = i / 384, c = i % 384;
        wqT[i] = qw[c * 9 + tap];
    } else if (i < 9576) {
        int j = i - 3456;
        int tap = j / 680, c = j % 680;
        wgT[j] = fw[c * 9 + tap];
    }
}

// ---------------------------------------------------------------------------
// im2col 3x3 (zero pad) -> bf16 patch matrix [M][640]: col = cc*10 + tap,
// tap 9 zero. thread = (t, cc), cc fast -> contiguous 20B stores per thread.
// ---------------------------------------------------------------------------
__global__ __launch_bounds__(256) void unfold_k(const float* __restrict__ buf, short* __restrict__ P) {
    int idx = blockIdx.x * 256 + threadIdx.x;    // < M*64
    int cc = idx & 63;
    int t  = idx >> 6;
    int l = t & 1023, n = t >> 10;
    int y = l >> 5, x = l & 31;
    const float* src = buf + (size_t)cc * M_TOK + (n << 10);
    float v[9];
#pragma unroll
    for (int ti = 0; ti < 3; ++ti) {
        int yy = y + ti - 1;
        bool yok = (yy >= 0 && yy < 32);
#pragma unroll
        for (int tj = 0; tj < 3; ++tj) {
            int xx = x + tj - 1;
            v[ti * 3 + tj] = (yok && xx >= 0 && xx < 32) ? src[(yy << 5) + xx] : 0.f;
        }
    }
    unsigned* dst = (unsigned*)(P + (size_t)t * 640 + cc * 10);
    dst[0] = f2b(v[0]) | ((unsigned)f2b(v[1]) << 16);
    dst[1] = f2b(v[2]) | ((unsigned)f2b(v[3]) << 16);
    dst[2] = f2b(v[4]) | ((unsigned)f2b(v[5]) << 16);
    dst[3] = f2b(v[6]) | ((unsigned)f2b(v[7]) << 16);
    dst[4] = (unsigned)f2b(v[8]);
}

// ---------------------------------------------------------------------------
// bf16 MFMA GEMM: out[M x N] (+=) A[M x K(lda)] * W[N x K]^T
// 128x64 tile, 4 waves (2x2), BK=32.
// ---------------------------------------------------------------------------
template <bool ADD, bool TROUT, bool OUTBF16, bool AF32>
__global__ __launch_bounds__(256) void mm_k(const void* __restrict__ Avp,
                                            const short* __restrict__ W,
                                            void* __restrict__ outp,
                                            int M, int N, int K, int lda) {
    __shared__ __align__(16) short As[128 * 40];
    __shared__ __align__(16) short Bs[64 * 40];
    const int tid = threadIdx.x;
    const int bm = blockIdx.x * 128;
    const int bn = blockIdx.y * 64;
    const int w = tid >> 6, lane = tid & 63;
    const int h = lane >> 4, l15 = lane & 15;
    const int wm = (w >> 1) * 64, wn = (w & 1) * 32;

    f32x4 acc[4][2];
#pragma unroll
    for (int i = 0; i < 4; ++i)
#pragma unroll
        for (int j = 0; j < 2; ++j) acc[i][j] = (f32x4){0.f, 0.f, 0.f, 0.f};

    for (int k0 = 0; k0 < K; k0 += 32) {
#pragma unroll
        for (int e = 0; e < 2; ++e) {
            int li = tid + e * 256;
            int row = li >> 2, c4 = li & 3;
            int gk = k0 + c4 * 8;
            size_t abase = (size_t)(bm + row) * lda + gk;
            short tmp[8];
            if (AF32) {
                const float* ap = (const float*)Avp + abase;
                if (gk + 8 <= K) {
                    float4 va = *(const float4*)ap;
                    float4 vb = *(const float4*)(ap + 4);
                    tmp[0] = (short)f2b(va.x); tmp[1] = (short)f2b(va.y);
                    tmp[2] = (short)f2b(va.z); tmp[3] = (short)f2b(va.w);
                    tmp[4] = (short)f2b(vb.x); tmp[5] = (short)f2b(vb.y);
                    tmp[6] = (short)f2b(vb.z); tmp[7] = (short)f2b(vb.w);
                } else {
#pragma unroll
                    for (int i = 0; i < 8; ++i) tmp[i] = (gk + i < K) ? (short)f2b(ap[i]) : (short)0;
                }
            } else {
                const short* ap = (const short*)Avp + abase;
                if (gk + 8 <= K) {
                    i32x2 a = *(const i32x2*)ap;
                    i32x2 b = *(const i32x2*)(ap + 4);
                    *(i32x2*)&tmp[0] = a; *(i32x2*)&tmp[4] = b;
                } else {
#pragma unroll
                    for (int i = 0; i < 8; ++i) tmp[i] = (gk + i < K) ? ap[i] : (short)0;
                }
            }
            *(i32x4*)&As[row * 40 + c4 * 8] = *(i32x4*)tmp;
        }
        {
            int row = tid >> 2, c4 = tid & 3;
            int gk = k0 + c4 * 8;
            int gn = bn + row;
            short tmp[8];
            if (gn < N && gk + 8 <= K) {
                const short* wp = W + (size_t)gn * K + gk;
                i32x2 a = *(const i32x2*)wp;
                i32x2 b = *(const i32x2*)(wp + 4);
                *(i32x2*)&tmp[0] = a; *(i32x2*)&tmp[4] = b;
            } else {
#pragma unroll
                for (int i = 0; i < 8; ++i)
                    tmp[i] = (gn < N && gk + i < K) ? W[(size_t)gn * K + gk + i] : (short)0;
            }
            *(i32x4*)&Bs[row * 40 + c4 * 8] = *(i32x4*)tmp;
        }
        __syncthreads();
        bf16x8 af[4], bf[2];
#pragma unroll
        for (int mi = 0; mi < 4; ++mi) af[mi] = *(const bf16x8*)&As[(wm + mi * 16 + l15) * 40 + h * 8];
#pragma unroll
        for (int nj = 0; nj < 2; ++nj) bf[nj] = *(const bf16x8*)&Bs[(wn + nj * 16 + l15) * 40 + h * 8];
#pragma unroll
        for (int mi = 0; mi < 4; ++mi)
#pragma unroll
            for (int nj = 0; nj < 2; ++nj) {
                if (TROUT)
                    acc[mi][nj] = __builtin_amdgcn_mfma_f32_16x16x32_bf16(bf[nj], af[mi], acc[mi][nj], 0, 0, 0);
                else
                    acc[mi][nj] = __builtin_amdgcn_mfma_f32_16x16x32_bf16(af[mi], bf[nj], acc[mi][nj], 0, 0, 0);
            }
        __syncthreads();
    }

    if (!TROUT) {
#pragma unroll
        for (int mi = 0; mi < 4; ++mi) {
#pragma unroll
            for (int nj = 0; nj < 2; ++nj) {
                int gn = bn + wn + nj * 16 + l15;
                if (gn < N) {
#pragma unroll
                    for (int r = 0; r < 4; ++r) {
                        int gm = bm + wm + mi * 16 + h * 4 + r;
                        float v = acc[mi][nj][r];
                        size_t oi = (size_t)gm * N + gn;
                        if (OUTBF16)      ((short*)outp)[oi] = (short)f2b(v);
                        else if (ADD)     ((float*)outp)[oi] += v;
                        else              ((float*)outp)[oi] = v;
                    }
                }
            }
        }
    } else {
#pragma unroll
        for (int mi = 0; mi < 4; ++mi) {
            int gm = bm + wm + mi * 16 + l15;
#pragma unroll
            for (int nj = 0; nj < 2; ++nj)
#pragma unroll
                for (int r = 0; r < 4; ++r) {
                    int gn = bn + wn + nj * 16 + h * 4 + r;
                    if (gn < N) ((float*)outp)[(size_t)gn * M + gm] = acc[mi][nj][r];
                }
        }
    }
}

// ---------------------------------------------------------------------------
// LayerNorm D=128, fp32 in -> bf16 out.
// ---------------------------------------------------------------------------
__global__ __launch_bounds__(256) void ln_k(const float* __restrict__ in,
                                            const float* __restrict__ w,
                                            const float* __restrict__ b,
                                            short* __restrict__ out) {
    int t = blockIdx.x * 4 + (threadIdx.x >> 6);
    int lane = threadIdx.x & 63;
    float2 v = *(const float2*)(in + (size_t)t * 128 + lane * 2);
    float s = v.x + v.y, sq = v.x * v.x + v.y * v.y;
#pragma unroll
    for (int off = 32; off > 0; off >>= 1) { s += __shfl_xor(s, off); sq += __shfl_xor(sq, off); }
    float mean = s * (1.f / 128.f);
    float var = sq * (1.f / 128.f) - mean * mean;
    float rstd = rsqrtf(var + 1e-5f);
    float2 wv = *(const float2*)(w + lane * 2);
    float2 bv = *(const float2*)(b + lane * 2);
    float ox = (v.x - mean) * rstd * wv.x + bv.x;
    float oy = (v.y - mean) * rstd * wv.y + bv.y;
    ((unsigned*)out)[(size_t)t * 64 + lane] = f2b(ox) | ((unsigned)f2b(oy) << 16);
}

// ---------------------------------------------------------------------------
// Fused qkv depthwise 3x3 + l2norm(q,k heads).
// ---------------------------------------------------------------------------
__global__ __launch_bounds__(256) void dwl2n_k(const short* __restrict__ in,
                                               const float* __restrict__ wqT,
                                               short* __restrict__ out) {
    int idx = blockIdx.x * 256 + threadIdx.x;    // < M*48
    int q = idx % 48;
    int t = idx / 48;
    int c0 = q * 8;
    int l = t & 1023, n = t >> 10;
    int y = l >> 5, x = l & 31;
    int tb = n << 10;

    float acc[8];
#pragma unroll
    for (int k = 0; k < 8; ++k) acc[k] = 0.f;

#pragma unroll
    for (int i = 0; i < 3; ++i) {
        int yy = y + i - 1;
        if (yy < 0 || yy >= 32) continue;
#pragma unroll
        for (int j = 0; j < 3; ++j) {
            int xx = x + j - 1;
            if (xx < 0 || xx >= 32) continue;
            bf16x8 d = *(const bf16x8*)(in + (size_t)(tb + (yy << 5) + xx) * 384 + c0);
            float4 wa = *(const float4*)(wqT + (i * 3 + j) * 384 + c0);
            float4 wb = *(const float4*)(wqT + (i * 3 + j) * 384 + c0 + 4);
            acc[0] += b2f((unsigned short)d[0]) * wa.x;
            acc[1] += b2f((unsigned short)d[1]) * wa.y;
            acc[2] += b2f((unsigned short)d[2]) * wa.z;
            acc[3] += b2f((unsigned short)d[3]) * wa.w;
            acc[4] += b2f((unsigned short)d[4]) * wb.x;
            acc[5] += b2f((unsigned short)d[5]) * wb.y;
            acc[6] += b2f((unsigned short)d[6]) * wb.z;
            acc[7] += b2f((unsigned short)d[7]) * wb.w;
        }
    }
    float ss = 0.f;
#pragma unroll
    for (int k = 0; k < 8; ++k) ss += acc[k] * acc[k];
    ss += __shfl_xor(ss, 1);
    ss += __shfl_xor(ss, 2);
    float sc = (c0 < 256) ? (1.f / fmaxf(sqrtf(ss), 1e-12f)) : 1.f;
    unsigned o[4];
#pragma unroll
    for (int k = 0; k < 4; ++k)
        o[k] = f2b(acc[2 * k] * sc) | ((unsigned)f2b(acc[2 * k + 1] * sc) << 16);
    *(i32x4*)(out + (size_t)t * 384 + c0) = *(i32x4*)o;
}

// ---------------------------------------------------------------------------
// Fused GDFN depthwise: dual 3x3 dwconv + exact gelu gate. out lda = 344.
// ---------------------------------------------------------------------------
__global__ __launch_bounds__(256) void gdfn2_k(const short* __restrict__ in,
                                               const float* __restrict__ wgT,
                                               short* __restrict__ out) {
    int idx = blockIdx.x * 256 + threadIdx.x;    // < M*43
    int q = idx % 43;
    int t = idx / 43;
    int c0 = q * 8;
    int l = t & 1023, n = t >> 10;
    int y = l >> 5, x = l & 31;
    int tb = n << 10;

    float a[8], g[8];
#pragma unroll
    for (int k = 0; k < 8; ++k) { a[k] = 0.f; g[k] = 0.f; }

#pragma unroll
    for (int i = 0; i < 3; ++i) {
        int yy = y + i - 1;
        if (yy < 0 || yy >= 32) continue;
#pragma unroll
        for (int j = 0; j < 3; ++j) {
            int xx = x + j - 1;
            if (xx < 0 || xx >= 32) continue;
            const short* p = in + (size_t)(tb + (yy << 5) + xx) * 680 + c0;
            bf16x8 d1 = *(const bf16x8*)p;
            i32x2 d2a = *(const i32x2*)(p + 340);
            i32x2 d2b = *(const i32x2*)(p + 344);
            short d2[8];
            *(i32x2*)&d2[0] = d2a; *(i32x2*)&d2[4] = d2b;
            const float* wp = wgT + (i * 3 + j) * 680 + c0;
            float4 w1a = *(const float4*)wp;
            float4 w1b = *(const float4*)(wp + 4);
            float w1[8] = {w1a.x, w1a.y, w1a.z, w1a.w, w1b.x, w1b.y, w1b.z, w1b.w};
            float w2[8];
#pragma unroll
            for (int k = 0; k < 8; ++k) w2[k] = wp[340 + k];
#pragma unroll
            for (int k = 0; k < 8; ++k) {
                a[k] += b2f((unsigned short)d1[k]) * w1[k];
                g[k] += b2f((unsigned short)d2[k]) * w2[k];
            }
        }
    }
    unsigned o[4];
#pragma unroll
    for (int k = 0; k < 4; ++k) {
        float r0 = 0.5f * a[2 * k] * (1.f + erff(a[2 * k] * 0.70710678118f)) * g[2 * k];
        float r1 = 0.5f * a[2 * k + 1] * (1.f + erff(a[2 * k + 1] * 0.70710678118f)) * g[2 * k + 1];
        o[k] = f2b(r0) | ((unsigned)f2b(r1) << 16);
    }
    short* op = out + (size_t)t * 344 + c0;
    if (q < 42) *(i32x4*)op = *(i32x4*)o;
    else        *(i32x2*)op = (i32x2){(int)o[0], (int)o[1]};
}

// ---------------------------------------------------------------------------
// MFMA flash attention v2: K-tile 64, zero-shuffle PV via pre-permuted V.
// Slot mapping: PV B-frag slot (h,j) of key-group g holds key
//   32g + 4h + (j&3) + 16*(j>>2)  — exactly where QK^T leaves P in registers.
// V staged as Vp[gran][j], gran = (g*4+h)*32 + c, XOR-swizzled (gran>>3)&7.
// ---------------------------------------------------------------------------
__global__ __launch_bounds__(256) void attn_k(const short* __restrict__ qkv,
                                              const float* __restrict__ temp,
                                              short* __restrict__ outp) {
    __shared__ __align__(16) short Ks[64 * 40];
    __shared__ __align__(16) short Vp[2048];
    const int bid = blockIdx.x;
    const int qt = bid & 15, nh = bid >> 4;
    const int hd = nh & 3, n = nh >> 2;
    const int tid = threadIdx.x;
    const int w = tid >> 6, lane = tid & 63;
    const int h = lane >> 4, l15 = lane & 15;
    const size_t base = (size_t)n * 1024 * 384;
    const int qrow = qt * 64 + w * 16 + l15;
    const float ts2 = temp[hd] * 1.44269504089f;   // log2(e) scaling -> exp2 softmax

    bf16x8 qf = *(const bf16x8*)(qkv + base + (size_t)qrow * 384 + hd * 32 + h * 8);
    f32x4 o0 = {0.f, 0.f, 0.f, 0.f}, o1 = {0.f, 0.f, 0.f, 0.f};
    float m = -1e30f, lsum = 0.f;

    // staging coords: thread -> (key, c4)
    const int skey = tid >> 2, sc4 = tid & 3;
    const int sg = skey >> 5, skey5 = skey & 31;
    const int sh = (skey5 >> 2) & 3;
    const int sj = (skey5 & 3) + ((skey5 >> 4) << 2);
    const int sgran0 = (sg * 4 + sh) * 32 + sc4 * 8;

    for (int j0 = 0; j0 < 1024; j0 += 64) {
        __syncthreads();
        const short* kp = qkv + base + (size_t)(j0 + skey) * 384 + 128 + hd * 32 + sc4 * 8;
        *(i32x4*)&Ks[skey * 40 + sc4 * 8] = *(const i32x4*)kp;
        i32x4 vv = *(const i32x4*)(kp + 128);
        short vs[8];
        *(i32x4*)vs = vv;
#pragma unroll
        for (int i = 0; i < 8; ++i) {
            int gran = sgran0 + i;
            gran ^= (gran >> 3) & 7;
            Vp[gran * 8 + sj] = vs[i];
        }
        __syncthreads();

        f32x4 z = {0.f, 0.f, 0.f, 0.f};
        bf16x8 kf0 = *(const bf16x8*)&Ks[l15 * 40 + h * 8];
        bf16x8 kf1 = *(const bf16x8*)&Ks[(16 + l15) * 40 + h * 8];
        bf16x8 kf2 = *(const bf16x8*)&Ks[(32 + l15) * 40 + h * 8];
        bf16x8 kf3 = *(const bf16x8*)&Ks[(48 + l15) * 40 + h * 8];
        f32x4 s0 = __builtin_amdgcn_mfma_f32_16x16x32_bf16(kf0, qf, z, 0, 0, 0);
        f32x4 s1 = __builtin_amdgcn_mfma_f32_16x16x32_bf16(kf1, qf, z, 0, 0, 0);
        f32x4 s2 = __builtin_amdgcn_mfma_f32_16x16x32_bf16(kf2, qf, z, 0, 0, 0);
        f32x4 s3 = __builtin_amdgcn_mfma_f32_16x16x32_bf16(kf3, qf, z, 0, 0, 0);

        float sv[16];
#pragma unroll
        for (int r = 0; r < 4; ++r) {
            sv[r]      = s0[r] * ts2;
            sv[4 + r]  = s1[r] * ts2;
            sv[8 + r]  = s2[r] * ts2;
            sv[12 + r] = s3[r] * ts2;
        }
        float tm = sv[0];
#pragma unroll
        for (int r = 1; r < 16; ++r) tm = fmaxf(tm, sv[r]);
        tm = fmaxf(tm, __shfl_xor(tm, 16));
        tm = fmaxf(tm, __shfl_xor(tm, 32));
        float nm = fmaxf(m, tm);
        float rs = exp2f(m - nm);
        float p[16], ps = 0.f;
#pragma unroll
        for (int r = 0; r < 16; ++r) { p[r] = exp2f(sv[r] - nm); ps += p[r]; }
        ps += __shfl_xor(ps, 16);
        ps += __shfl_xor(ps, 32);
        lsum = lsum * rs + ps;
        m = nm;
#pragma unroll
        for (int r = 0; r < 4; ++r) { o0[r] *= rs; o1[r] *= rs; }

        // P is already in B-frag slot order: pfA = keys 0-31, pfB = keys 32-63
        union { unsigned u[4]; bf16x8 v; } pfA, pfB;
#pragma unroll
        for (int r = 0; r < 4; ++r) {
            pfA.u[r] = cvtpk(p[2 * r], p[2 * r + 1]);
            pfB.u[r] = cvtpk(p[8 + 2 * r], p[8 + 2 * r + 1]);
        }
        int gr;
        gr = h * 32 + l15;              gr ^= (gr >> 3) & 7;  bf16x8 va0 = *(const bf16x8*)&Vp[gr * 8];
        gr = h * 32 + 16 + l15;         gr ^= (gr >> 3) & 7;  bf16x8 va1 = *(const bf16x8*)&Vp[gr * 8];
        gr = (4 + h) * 32 + l15;        gr ^= (gr >> 3) & 7;  bf16x8 vb0 = *(const bf16x8*)&Vp[gr * 8];
        gr = (4 + h) * 32 + 16 + l15;   gr ^= (gr >> 3) & 7;  bf16x8 vb1 = *(const bf16x8*)&Vp[gr * 8];
        o0 = __builtin_amdgcn_mfma_f32_16x16x32_bf16(va0, pfA.v, o0, 0, 0, 0);
        o1 = __builtin_amdgcn_mfma_f32_16x16x32_bf16(va1, pfA.v, o1, 0, 0, 0);
        o0 = __builtin_amdgcn_mfma_f32_16x16x32_bf16(vb0, pfB.v, o0, 0, 0, 0);
        o1 = __builtin_amdgcn_mfma_f32_16x16x32_bf16(vb1, pfB.v, o1, 0, 0, 0);
    }
    float inv = 1.f / lsum;
    size_t ob = ((size_t)n * 1024 + qrow) * 128 + hd * 32;
    unsigned u;
    u = f2b(o0[0] * inv) | ((unsigned)f2b(o0[1] * inv) << 16); *(unsigned*)(outp + ob + h * 4) = u;
    u = f2b(o0[2] * inv) | ((unsigned)f2b(o0[3] * inv) << 16); *(unsigned*)(outp + ob + h * 4 + 2) = u;
    u = f2b(o1[0] * inv) | ((unsigned)f2b(o1[1] * inv) << 16); *(unsigned*)(outp + ob + 16 + h * 4) = u;
    u = f2b(o1[2] * inv) | ((unsigned)f2b(o1[3] * inv) << 16); *(unsigned*)(outp + ob + 16 + h * 4 + 2) = u;
}

// ---------------------------------------------------------------------------
extern "C" void kernel_launch(void* const* d_in, const int* in_sizes, int n_in,
                              void* d_out, int out_size, void* d_ws, size_t ws_size,
                              hipStream_t stream) {
    const float* buffer      = (const float*)d_in[0];
    const float* mlp_w       = (const float*)d_in[1];
    const float* ln_attn_w   = (const float*)d_in[2];
    const float* ln_attn_b   = (const float*)d_in[3];
    const float* ln_ffn_w    = (const float*)d_in[4];
    const float* ln_ffn_b    = (const float*)d_in[5];
    const float* qkv_w       = (const float*)d_in[6];
    const float* qkv_dw_w    = (const float*)d_in[7];
    const float* temperature = (const float*)d_in[8];
    const float* proj_attn_w = (const float*)d_in[9];
    const float* ffn_in_w    = (const float*)d_in[10];
    const float* ffn_dw_w    = (const float*)d_in[11];
    const float* ffn_out_w   = (const float*)d_in[12];
    const float* proj3d_w    = (const float*)d_in[13];

    char* wsb = (char*)d_ws;
    short* Wbf     = (short*)wsb;                 // 286208 bf16 weights
    short* mlpW    = Wbf;                         // [128][640] (padded taps)
    short* qkvW    = Wbf + 81920;                 // [384][128]
    short* projW   = Wbf + 131072;                // [128][128]
    short* ffnInW  = Wbf + 147456;                // [680][128]
    short* ffnOutW = Wbf + 234496;                // [128][340]
    short* p3dW    = Wbf + 278016;                // [64][128]
    float* wqT     = (float*)(wsb + 573440);      // [9][384] f32
    float* wgT     = (float*)(wsb + 587264);      // [9][680] f32
    short* PatchB  = (short*)(wsb + 611840);      // [M][640] bf16
    float* tok     = (float*)(wsb + 33379840);    // [M][128] f32
    short* LNbf    = (short*)(wsb + 46487040);    // [M][128] bf16
    short* QKVpre  = (short*)(wsb + 53040640);    // [M][384] bf16
    short* qkvb    = (short*)(wsb + 72701440);    // [M][384] bf16
    short* AObf    = (short*)(wsb + 92362240);    // [M][128] bf16
    short* F1      = (short*)(wsb + 98915840);    // [M][680] bf16
    short* G       = (short*)(wsb + 133731840);   // [M][344] bf16 (lda 344)

    dim3 blk(256);

    cvtw_k<<<1118, blk, 0, stream>>>(mlp_w, qkv_w, proj_attn_w, ffn_in_w, ffn_out_w, proj3d_w, Wbf);
    twp_k<<<38, blk, 0, stream>>>(qkv_dw_w, ffn_dw_w, wqT, wgT);
    unfold_k<<<6400, blk, 0, stream>>>(buffer, PatchB);

    // S2T: tok = patches @ mlp_w^T (f32 out), K padded to 640
    mm_k<false, false, false, false><<<dim3(200, 2), blk, 0, stream>>>(PatchB, mlpW, tok, M_TOK, 128, 640, 640);
    ln_k<<<6400, blk, 0, stream>>>(tok, ln_attn_w, ln_attn_b, LNbf);
    // qkv 1x1 (bf16 out)
    mm_k<false, false, true, false><<<dim3(200, 6), blk, 0, stream>>>(LNbf, qkvW, QKVpre, M_TOK, 384, 128, 128);
    // fused dwconv + l2norm
    dwl2n_k<<<4800, blk, 0, stream>>>(QKVpre, wqT, qkvb);
    attn_k<<<1600, blk, 0, stream>>>(qkvb, temperature, AObf);
    // proj + residual
    mm_k<true, false, false, false><<<dim3(200, 2), blk, 0, stream>>>(AObf, projW, tok, M_TOK, 128, 128, 128);
    ln_k<<<6400, blk, 0, stream>>>(tok, ln_ffn_w, ln_ffn_b, LNbf);
    // ffn_in 1x1 (bf16 out)
    mm_k<false, false, true, false><<<dim3(200, 11), blk, 0, stream>>>(LNbf, ffnInW, F1, M_TOK, 680, 128, 128);
    // fused GDFN dwconv + gelu gate
    gdfn2_k<<<4300, blk, 0, stream>>>(F1, wgT, G);
    // ffn_out + residual (A lda = 344)
    mm_k<true, false, false, false><<<dim3(200, 2), blk, 0, stream>>>(G, ffnOutW, tok, M_TOK, 128, 340, 344);
    // Token2SAI (transposed product, coalesced)
    mm_k<false, true, false, true><<<dim3(200, 1), blk, 0, stream>>>(tok, p3dW, d_out, M_TOK, 64, 128, 128);
}

// Round 5
// 249.818 us; speedup vs baseline: 4.6256x; 1.0121x over previous
//
#include <hip/hip_runtime.h>
#include <math.h>

#define M_TOK 25600   // 25 images * 1024 tokens

typedef __attribute__((ext_vector_type(8))) short bf16x8;
typedef __attribute__((ext_vector_type(4))) float f32x4;
typedef __attribute__((ext_vector_type(4))) int   i32x4;
typedef __attribute__((ext_vector_type(2))) int   i32x2;

__device__ __forceinline__ unsigned short f2b(float x) {
    unsigned u = __builtin_bit_cast(unsigned, x);
    return (unsigned short)((u + 0x7fffu + ((u >> 16) & 1u)) >> 16);
}
__device__ __forceinline__ float b2f(unsigned short h) {
    unsigned u = ((unsigned)h) << 16;
    return __builtin_bit_cast(float, u);
}
__device__ __forceinline__ unsigned cvtpk(float lo, float hi) {
    unsigned r;
    asm("v_cvt_pk_bf16_f32 %0, %1, %2" : "=v"(r) : "v"(lo), "v"(hi));
    return r;
}

// ---------------------------------------------------------------------------
// Weight fp32->bf16 conversion. mlp_w is re-laid-out [128][64][10] (tap 9 = 0)
// so the im2col patch matrix can use K=640 with 20B-aligned rows.
// ---------------------------------------------------------------------------
__global__ __launch_bounds__(256) void cvtw_k(const float* __restrict__ s0, const float* __restrict__ s1,
                                              const float* __restrict__ s2, const float* __restrict__ s3,
                                              const float* __restrict__ s4, const float* __restrict__ s5,
                                              short* __restrict__ dst) {
    int i = blockIdx.x * 256 + threadIdx.x;      // < 286208
    if (i < 81920) {
        int tap = i % 10, q = i / 10;            // q = d*64 + cc
        dst[i] = (tap < 9) ? (short)f2b(s0[q * 9 + tap]) : (short)0;
        return;
    }
    const float* s; int off;
    if      (i < 131072) { s = s1; off = i - 81920; }
    else if (i < 147456) { s = s2; off = i - 131072; }
    else if (i < 234496) { s = s3; off = i - 147456; }
    else if (i < 278016) { s = s4; off = i - 234496; }
    else                 { s = s5; off = i - 278016; }
    dst[i] = (short)f2b(s[off]);
}

// ---------------------------------------------------------------------------
// Depthwise-weight transpose: [C][9] -> [9][C] (f32), qkv (384) + ffn (680)
// ---------------------------------------------------------------------------
__global__ __launch_bounds__(256) void twp_k(const float* __restrict__ qw,
                                             const float* __restrict__ fw,
                                             float* __restrict__ wqT,
                                             float* __restrict__ wgT) {
    int i = blockIdx.x * 256 + threadIdx.x;      // < 9576
    if (i < 3456) {
        int tap = i / 384, c = i % 384;
        wqT[i] = qw[c * 9 + tap];
    } else if (i < 9576) {
        int j = i - 3456;
        int tap = j / 680, c = j % 680;
        wgT[j] = fw[c * 9 + tap];
    }
}

// ---------------------------------------------------------------------------
// im2col 3x3 (zero pad) -> bf16 patch matrix [M][640]: col = cc*10 + tap,
// tap 9 zero. thread = (t, cc), cc fast -> contiguous 20B stores per thread.
// ---------------------------------------------------------------------------
__global__ __launch_bounds__(256) void unfold_k(const float* __restrict__ buf, short* __restrict__ P) {
    int idx = blockIdx.x * 256 + threadIdx.x;    // < M*64
    int cc = idx & 63;
    int t  = idx >> 6;
    int l = t & 1023, n = t >> 10;
    int y = l >> 5, x = l & 31;
    const float* src = buf + (size_t)cc * M_TOK + (n << 10);
    float v[9];
#pragma unroll
    for (int ti = 0; ti < 3; ++ti) {
        int yy = y + ti - 1;
        bool yok = (yy >= 0 && yy < 32);
#pragma unroll
        for (int tj = 0; tj < 3; ++tj) {
            int xx = x + tj - 1;
            v[ti * 3 + tj] = (yok && xx >= 0 && xx < 32) ? src[(yy << 5) + xx] : 0.f;
        }
    }
    unsigned* dst = (unsigned*)(P + (size_t)t * 640 + cc * 10);
    dst[0] = f2b(v[0]) | ((unsigned)f2b(v[1]) << 16);
    dst[1] = f2b(v[2]) | ((unsigned)f2b(v[3]) << 16);
    dst[2] = f2b(v[4]) | ((unsigned)f2b(v[5]) << 16);
    dst[3] = f2b(v[6]) | ((unsigned)f2b(v[7]) << 16);
    dst[4] = (unsigned)f2b(v[8]);
}

// ---------------------------------------------------------------------------
// bf16 MFMA GEMM: out[M x N] (+=) A[M x K(lda)] * W[N x K]^T
// 128x64 tile, 4 waves (2x2), BK=32.
// ---------------------------------------------------------------------------
template <bool ADD, bool TROUT, bool OUTBF16, bool AF32>
__global__ __launch_bounds__(256) void mm_k(const void* __restrict__ Avp,
                                            const short* __restrict__ W,
                                            void* __restrict__ outp,
                                            int M, int N, int K, int lda) {
    __shared__ __align__(16) short As[128 * 40];
    __shared__ __align__(16) short Bs[64 * 40];
    const int tid = threadIdx.x;
    const int bm = blockIdx.x * 128;
    const int bn = blockIdx.y * 64;
    const int w = tid >> 6, lane = tid & 63;
    const int h = lane >> 4, l15 = lane & 15;
    const int wm = (w >> 1) * 64, wn = (w & 1) * 32;

    f32x4 acc[4][2];
#pragma unroll
    for (int i = 0; i < 4; ++i)
#pragma unroll
        for (int j = 0; j < 2; ++j) acc[i][j] = (f32x4){0.f, 0.f, 0.f, 0.f};

    for (int k0 = 0; k0 < K; k0 += 32) {
#pragma unroll
        for (int e = 0; e < 2; ++e) {
            int li = tid + e * 256;
            int row = li >> 2, c4 = li & 3;
            int gk = k0 + c4 * 8;
            size_t abase = (size_t)(bm + row) * lda + gk;
            short tmp[8];
            if (AF32) {
                const float* ap = (const float*)Avp + abase;
                if (gk + 8 <= K) {
                    float4 va = *(const float4*)ap;
                    float4 vb = *(const float4*)(ap + 4);
                    tmp[0] = (short)f2b(va.x); tmp[1] = (short)f2b(va.y);
                    tmp[2] = (short)f2b(va.z); tmp[3] = (short)f2b(va.w);
                    tmp[4] = (short)f2b(vb.x); tmp[5] = (short)f2b(vb.y);
                    tmp[6] = (short)f2b(vb.z); tmp[7] = (short)f2b(vb.w);
                } else {
#pragma unroll
                    for (int i = 0; i < 8; ++i) tmp[i] = (gk + i < K) ? (short)f2b(ap[i]) : (short)0;
                }
            } else {
                const short* ap = (const short*)Avp + abase;
                if (gk + 8 <= K) {
                    i32x2 a = *(const i32x2*)ap;
                    i32x2 b = *(const i32x2*)(ap + 4);
                    *(i32x2*)&tmp[0] = a; *(i32x2*)&tmp[4] = b;
                } else {
#pragma unroll
                    for (int i = 0; i < 8; ++i) tmp[i] = (gk + i < K) ? ap[i] : (short)0;
                }
            }
            *(i32x4*)&As[row * 40 + c4 * 8] = *(i32x4*)tmp;
        }
        {
            int row = tid >> 2, c4 = tid & 3;
            int gk = k0 + c4 * 8;
            int gn = bn + row;
            short tmp[8];
            if (gn < N && gk + 8 <= K) {
                const short* wp = W + (size_t)gn * K + gk;
                i32x2 a = *(const i32x2*)wp;
                i32x2 b = *(const i32x2*)(wp + 4);
                *(i32x2*)&tmp[0] = a; *(i32x2*)&tmp[4] = b;
            } else {
#pragma unroll
                for (int i = 0; i < 8; ++i)
                    tmp[i] = (gn < N && gk + i < K) ? W[(size_t)gn * K + gk + i] : (short)0;
            }
            *(i32x4*)&Bs[row * 40 + c4 * 8] = *(i32x4*)tmp;
        }
        __syncthreads();
        bf16x8 af[4], bf[2];
#pragma unroll
        for (int mi = 0; mi < 4; ++mi) af[mi] = *(const bf16x8*)&As[(wm + mi * 16 + l15) * 40 + h * 8];
#pragma unroll
        for (int nj = 0; nj < 2; ++nj) bf[nj] = *(const bf16x8*)&Bs[(wn + nj * 16 + l15) * 40 + h * 8];
#pragma unroll
        for (int mi = 0; mi < 4; ++mi)
#pragma unroll
            for (int nj = 0; nj < 2; ++nj) {
                if (TROUT)
                    acc[mi][nj] = __builtin_amdgcn_mfma_f32_16x16x32_bf16(bf[nj], af[mi], acc[mi][nj], 0, 0, 0);
                else
                    acc[mi][nj] = __builtin_amdgcn_mfma_f32_16x16x32_bf16(af[mi], bf[nj], acc[mi][nj], 0, 0, 0);
            }
        __syncthreads();
    }

    if (!TROUT) {
#pragma unroll
        for (int mi = 0; mi < 4; ++mi) {
#pragma unroll
            for (int nj = 0; nj < 2; ++nj) {
                int gn = bn + wn + nj * 16 + l15;
                if (gn < N) {
#pragma unroll
                    for (int r = 0; r < 4; ++r) {
                        int gm = bm + wm + mi * 16 + h * 4 + r;
                        float v = acc[mi][nj][r];
                        size_t oi = (size_t)gm * N + gn;
                        if (OUTBF16)      ((short*)outp)[oi] = (short)f2b(v);
                        else if (ADD)     ((float*)outp)[oi] += v;
                        else              ((float*)outp)[oi] = v;
                    }
                }
            }
        }
    } else {
#pragma unroll
        for (int mi = 0; mi < 4; ++mi) {
            int gm = bm + wm + mi * 16 + l15;
#pragma unroll
            for (int nj = 0; nj < 2; ++nj)
#pragma unroll
                for (int r = 0; r < 4; ++r) {
                    int gn = bn + wn + nj * 16 + h * 4 + r;
                    if (gn < N) ((float*)outp)[(size_t)gn * M + gm] = acc[mi][nj][r];
                }
        }
    }
}

// ---------------------------------------------------------------------------
// LayerNorm D=128, fp32 in -> bf16 out.
// ---------------------------------------------------------------------------
__global__ __launch_bounds__(256) void ln_k(const float* __restrict__ in,
                                            const float* __restrict__ w,
                                            const float* __restrict__ b,
                                            short* __restrict__ out) {
    int t = blockIdx.x * 4 + (threadIdx.x >> 6);
    int lane = threadIdx.x & 63;
    float2 v = *(const float2*)(in + (size_t)t * 128 + lane * 2);
    float s = v.x + v.y, sq = v.x * v.x + v.y * v.y;
#pragma unroll
    for (int off = 32; off > 0; off >>= 1) { s += __shfl_xor(s, off); sq += __shfl_xor(sq, off); }
    float mean = s * (1.f / 128.f);
    float var = sq * (1.f / 128.f) - mean * mean;
    float rstd = rsqrtf(var + 1e-5f);
    float2 wv = *(const float2*)(w + lane * 2);
    float2 bv = *(const float2*)(b + lane * 2);
    float ox = (v.x - mean) * rstd * wv.x + bv.x;
    float oy = (v.y - mean) * rstd * wv.y + bv.y;
    ((unsigned*)out)[(size_t)t * 64 + lane] = f2b(ox) | ((unsigned)f2b(oy) << 16);
}

// ---------------------------------------------------------------------------
// Fused qkv depthwise 3x3 + l2norm(q,k heads).
// ---------------------------------------------------------------------------
__global__ __launch_bounds__(256) void dwl2n_k(const short* __restrict__ in,
                                               const float* __restrict__ wqT,
                                               short* __restrict__ out) {
    int idx = blockIdx.x * 256 + threadIdx.x;    // < M*48
    int q = idx % 48;
    int t = idx / 48;
    int c0 = q * 8;
    int l = t & 1023, n = t >> 10;
    int y = l >> 5, x = l & 31;
    int tb = n << 10;

    float acc[8];
#pragma unroll
    for (int k = 0; k < 8; ++k) acc[k] = 0.f;

#pragma unroll
    for (int i = 0; i < 3; ++i) {
        int yy = y + i - 1;
        if (yy < 0 || yy >= 32) continue;
#pragma unroll
        for (int j = 0; j < 3; ++j) {
            int xx = x + j - 1;
            if (xx < 0 || xx >= 32) continue;
            bf16x8 d = *(const bf16x8*)(in + (size_t)(tb + (yy << 5) + xx) * 384 + c0);
            float4 wa = *(const float4*)(wqT + (i * 3 + j) * 384 + c0);
            float4 wb = *(const float4*)(wqT + (i * 3 + j) * 384 + c0 + 4);
            acc[0] += b2f((unsigned short)d[0]) * wa.x;
            acc[1] += b2f((unsigned short)d[1]) * wa.y;
            acc[2] += b2f((unsigned short)d[2]) * wa.z;
            acc[3] += b2f((unsigned short)d[3]) * wa.w;
            acc[4] += b2f((unsigned short)d[4]) * wb.x;
            acc[5] += b2f((unsigned short)d[5]) * wb.y;
            acc[6] += b2f((unsigned short)d[6]) * wb.z;
            acc[7] += b2f((unsigned short)d[7]) * wb.w;
        }
    }
    float ss = 0.f;
#pragma unroll
    for (int k = 0; k < 8; ++k) ss += acc[k] * acc[k];
    ss += __shfl_xor(ss, 1);
    ss += __shfl_xor(ss, 2);
    float sc = (c0 < 256) ? (1.f / fmaxf(sqrtf(ss), 1e-12f)) : 1.f;
    unsigned o[4];
#pragma unroll
    for (int k = 0; k < 4; ++k)
        o[k] = f2b(acc[2 * k] * sc) | ((unsigned)f2b(acc[2 * k + 1] * sc) << 16);
    *(i32x4*)(out + (size_t)t * 384 + c0) = *(i32x4*)o;
}

// ---------------------------------------------------------------------------
// Fused GDFN depthwise: dual 3x3 dwconv + exact gelu gate. out lda = 344.
// ---------------------------------------------------------------------------
__global__ __launch_bounds__(256) void gdfn2_k(const short* __restrict__ in,
                                               const float* __restrict__ wgT,
                                               short* __restrict__ out) {
    int idx = blockIdx.x * 256 + threadIdx.x;    // < M*43
    int q = idx % 43;
    int t = idx / 43;
    int c0 = q * 8;
    int l = t & 1023, n = t >> 10;
    int y = l >> 5, x = l & 31;
    int tb = n << 10;

    float a[8], g[8];
#pragma unroll
    for (int k = 0; k < 8; ++k) { a[k] = 0.f; g[k] = 0.f; }

#pragma unroll
    for (int i = 0; i < 3; ++i) {
        int yy = y + i - 1;
        if (yy < 0 || yy >= 32) continue;
#pragma unroll
        for (int j = 0; j < 3; ++j) {
            int xx = x + j - 1;
            if (xx < 0 || xx >= 32) continue;
            const short* p = in + (size_t)(tb + (yy << 5) + xx) * 680 + c0;
            bf16x8 d1 = *(const bf16x8*)p;
            i32x2 d2a = *(const i32x2*)(p + 340);
            i32x2 d2b = *(const i32x2*)(p + 344);
            short d2[8];
            *(i32x2*)&d2[0] = d2a; *(i32x2*)&d2[4] = d2b;
            const float* wp = wgT + (i * 3 + j) * 680 + c0;
            float4 w1a = *(const float4*)wp;
            float4 w1b = *(const float4*)(wp + 4);
            float w1[8] = {w1a.x, w1a.y, w1a.z, w1a.w, w1b.x, w1b.y, w1b.z, w1b.w};
            float w2[8];
#pragma unroll
            for (int k = 0; k < 8; ++k) w2[k] = wp[340 + k];
#pragma unroll
            for (int k = 0; k < 8; ++k) {
                a[k] += b2f((unsigned short)d1[k]) * w1[k];
                g[k] += b2f((unsigned short)d2[k]) * w2[k];
            }
        }
    }
    unsigned o[4];
#pragma unroll
    for (int k = 0; k < 4; ++k) {
        float r0 = 0.5f * a[2 * k] * (1.f + erff(a[2 * k] * 0.70710678118f)) * g[2 * k];
        float r1 = 0.5f * a[2 * k + 1] * (1.f + erff(a[2 * k + 1] * 0.70710678118f)) * g[2 * k + 1];
        o[k] = f2b(r0) | ((unsigned)f2b(r1) << 16);
    }
    short* op = out + (size_t)t * 344 + c0;
    if (q < 42) *(i32x4*)op = *(i32x4*)o;
    else        *(i32x2*)op = (i32x2){(int)o[0], (int)o[1]};
}

// ---------------------------------------------------------------------------
// MFMA flash attention v3:
//  - 128 q-rows per block (800 blocks), K-tile 64, zero-shuffle PV
//  - fixed-bound softmax: q,k l2-normed => |q.k|<=1 => static max bound,
//    no running max, no rescale, denominator reduced once at the end
//  - double-buffered LDS, ONE barrier per tile, register prefetch of t+1
// ---------------------------------------------------------------------------
__global__ __launch_bounds__(256) void attn_k(const short* __restrict__ qkv,
                                              const float* __restrict__ temp,
                                              short* __restrict__ outp) {
    __shared__ __align__(16) short Ks[2][64 * 40];
    __shared__ __align__(16) short Vp[2][2048];
    const int bid = blockIdx.x;              // 800 = 25n * 4hd * 8qt
    const int qt = bid & 7, nh = bid >> 3;
    const int hd = nh & 3, n = nh >> 2;
    const int tid = threadIdx.x;
    const int w = tid >> 6, lane = tid & 63;
    const int h = lane >> 4, l15 = lane & 15;
    const size_t base = (size_t)n * 1024 * 384;
    const int qrowA = qt * 128 + w * 16 + l15;
    const float ts2 = temp[hd] * 1.44269504089f;       // exp2-domain temperature
    const float nbound = -(fabsf(ts2) + 0.25f);        // static softmax shift

    bf16x8 qfA = *(const bf16x8*)(qkv + base + (size_t)qrowA * 384 + hd * 32 + h * 8);
    bf16x8 qfB = *(const bf16x8*)(qkv + base + (size_t)(qrowA + 64) * 384 + hd * 32 + h * 8);
    f32x4 oA0 = {0.f,0.f,0.f,0.f}, oA1 = {0.f,0.f,0.f,0.f};
    f32x4 oB0 = {0.f,0.f,0.f,0.f}, oB1 = {0.f,0.f,0.f,0.f};
    float psA = 0.f, psB = 0.f;

    // staging coords: thread -> (key, c4); V permuted to PV B-frag slot order
    const int skey = tid >> 2, sc4 = tid & 3;
    const int sg = skey >> 5, skey5 = skey & 31;
    const int sh = (skey5 >> 2) & 3;
    const int sj = (skey5 & 3) + ((skey5 >> 4) << 2);
    const int sgran0 = (sg * 4 + sh) * 32 + sc4 * 8;
    const short* kbase = qkv + base + (size_t)skey * 384 + 128 + hd * 32 + sc4 * 8;

    i32x4 kreg = *(const i32x4*)kbase;
    i32x4 vreg = *(const i32x4*)(kbase + 128);

    for (int t = 0; t < 16; ++t) {
        const int nb = t & 1;
        // write tile t into buf nb
        *(i32x4*)&Ks[nb][skey * 40 + sc4 * 8] = kreg;
        {
            short vs[8];
            *(i32x4*)vs = vreg;
#pragma unroll
            for (int i = 0; i < 8; ++i) {
                int gran = sgran0 + i;
                gran ^= (gran >> 3) & 7;
                Vp[nb][gran * 8 + sj] = vs[i];
            }
        }
        // prefetch tile t+1 into regs (in flight across barrier+compute)
        if (t < 15) {
            const short* kp = kbase + (size_t)(t + 1) * 64 * 384;
            kreg = *(const i32x4*)kp;
            vreg = *(const i32x4*)(kp + 128);
        }
        __syncthreads();

        const bf16x8 kf0 = *(const bf16x8*)&Ks[nb][l15 * 40 + h * 8];
        const bf16x8 kf1 = *(const bf16x8*)&Ks[nb][(16 + l15) * 40 + h * 8];
        const bf16x8 kf2 = *(const bf16x8*)&Ks[nb][(32 + l15) * 40 + h * 8];
        const bf16x8 kf3 = *(const bf16x8*)&Ks[nb][(48 + l15) * 40 + h * 8];
        int gr0 = h * 32 + l15;            gr0 ^= (gr0 >> 3) & 7;
        int gr1 = h * 32 + 16 + l15;       gr1 ^= (gr1 >> 3) & 7;
        int gr2 = (4 + h) * 32 + l15;      gr2 ^= (gr2 >> 3) & 7;
        int gr3 = (4 + h) * 32 + 16 + l15; gr3 ^= (gr3 >> 3) & 7;
        const bf16x8 va0 = *(const bf16x8*)&Vp[nb][gr0 * 8];
        const bf16x8 va1 = *(const bf16x8*)&Vp[nb][gr1 * 8];
        const bf16x8 vb0 = *(const bf16x8*)&Vp[nb][gr2 * 8];
        const bf16x8 vb1 = *(const bf16x8*)&Vp[nb][gr3 * 8];
        const f32x4 z = {0.f, 0.f, 0.f, 0.f};

        // ---- q-set A ----
        {
            f32x4 s0 = __builtin_amdgcn_mfma_f32_16x16x32_bf16(kf0, qfA, z, 0, 0, 0);
            f32x4 s1 = __builtin_amdgcn_mfma_f32_16x16x32_bf16(kf1, qfA, z, 0, 0, 0);
            f32x4 s2 = __builtin_amdgcn_mfma_f32_16x16x32_bf16(kf2, qfA, z, 0, 0, 0);
            f32x4 s3 = __builtin_amdgcn_mfma_f32_16x16x32_bf16(kf3, qfA, z, 0, 0, 0);
            float p[16];
#pragma unroll
            for (int r = 0; r < 4; ++r) {
                p[r]      = exp2f(fmaf(s0[r], ts2, nbound));
                p[4 + r]  = exp2f(fmaf(s1[r], ts2, nbound));
                p[8 + r]  = exp2f(fmaf(s2[r], ts2, nbound));
                p[12 + r] = exp2f(fmaf(s3[r], ts2, nbound));
            }
#pragma unroll
            for (int r = 0; r < 16; ++r) psA += p[r];
            union { unsigned u[4]; bf16x8 v; } pf1, pf2;
#pragma unroll
            for (int r = 0; r < 4; ++r) {
                pf1.u[r] = cvtpk(p[2 * r], p[2 * r + 1]);
                pf2.u[r] = cvtpk(p[8 + 2 * r], p[8 + 2 * r + 1]);
            }
            oA0 = __builtin_amdgcn_mfma_f32_16x16x32_bf16(va0, pf1.v, oA0, 0, 0, 0);
            oA1 = __builtin_amdgcn_mfma_f32_16x16x32_bf16(va1, pf1.v, oA1, 0, 0, 0);
            oA0 = __builtin_amdgcn_mfma_f32_16x16x32_bf16(vb0, pf2.v, oA0, 0, 0, 0);
            oA1 = __builtin_amdgcn_mfma_f32_16x16x32_bf16(vb1, pf2.v, oA1, 0, 0, 0);
        }
        // ---- q-set B ----
        {
            f32x4 s0 = __builtin_amdgcn_mfma_f32_16x16x32_bf16(kf0, qfB, z, 0, 0, 0);
            f32x4 s1 = __builtin_amdgcn_mfma_f32_16x16x32_bf16(kf1, qfB, z, 0, 0, 0);
            f32x4 s2 = __builtin_amdgcn_mfma_f32_16x16x32_bf16(kf2, qfB, z, 0, 0, 0);
            f32x4 s3 = __builtin_amdgcn_mfma_f32_16x16x32_bf16(kf3, qfB, z, 0, 0, 0);
            float p[16];
#pragma unroll
            for (int r = 0; r < 4; ++r) {
                p[r]      = exp2f(fmaf(s0[r], ts2, nbound));
                p[4 + r]  = exp2f(fmaf(s1[r], ts2, nbound));
                p[8 + r]  = exp2f(fmaf(s2[r], ts2, nbound));
                p[12 + r] = exp2f(fmaf(s3[r], ts2, nbound));
            }
#pragma unroll
            for (int r = 0; r < 16; ++r) psB += p[r];
            union { unsigned u[4]; bf16x8 v; } pf1, pf2;
#pragma unroll
            for (int r = 0; r < 4; ++r) {
                pf1.u[r] = cvtpk(p[2 * r], p[2 * r + 1]);
                pf2.u[r] = cvtpk(p[8 + 2 * r], p[8 + 2 * r + 1]);
            }
            oB0 = __builtin_amdgcn_mfma_f32_16x16x32_bf16(va0, pf1.v, oB0, 0, 0, 0);
            oB1 = __builtin_amdgcn_mfma_f32_16x16x32_bf16(va1, pf1.v, oB1, 0, 0, 0);
            oB0 = __builtin_amdgcn_mfma_f32_16x16x32_bf16(vb0, pf2.v, oB0, 0, 0, 0);
            oB1 = __builtin_amdgcn_mfma_f32_16x16x32_bf16(vb1, pf2.v, oB1, 0, 0, 0);
        }
    }

    psA += __shfl_xor(psA, 16); psA += __shfl_xor(psA, 32);
    psB += __shfl_xor(psB, 16); psB += __shfl_xor(psB, 32);
    float invA = 1.f / psA, invB = 1.f / psB;

    size_t obA = ((size_t)n * 1024 + qrowA) * 128 + hd * 32;
    size_t obB = obA + (size_t)64 * 128;
    unsigned u;
    u = f2b(oA0[0] * invA) | ((unsigned)f2b(oA0[1] * invA) << 16); *(unsigned*)(outp + obA + h * 4) = u;
    u = f2b(oA0[2] * invA) | ((unsigned)f2b(oA0[3] * invA) << 16); *(unsigned*)(outp + obA + h * 4 + 2) = u;
    u = f2b(oA1[0] * invA) | ((unsigned)f2b(oA1[1] * invA) << 16); *(unsigned*)(outp + obA + 16 + h * 4) = u;
    u = f2b(oA1[2] * invA) | ((unsigned)f2b(oA1[3] * invA) << 16); *(unsigned*)(outp + obA + 16 + h * 4 + 2) = u;
    u = f2b(oB0[0] * invB) | ((unsigned)f2b(oB0[1] * invB) << 16); *(unsigned*)(outp + obB + h * 4) = u;
    u = f2b(oB0[2] * invB) | ((unsigned)f2b(oB0[3] * invB) << 16); *(unsigned*)(outp + obB + h * 4 + 2) = u;
    u = f2b(oB1[0] * invB) | ((unsigned)f2b(oB1[1] * invB) << 16); *(unsigned*)(outp + obB + 16 + h * 4) = u;
    u = f2b(oB1[2] * invB) | ((unsigned)f2b(oB1[3] * invB) << 16); *(unsigned*)(outp + obB + 16 + h * 4 + 2) = u;
}

// ---------------------------------------------------------------------------
extern "C" void kernel_launch(void* const* d_in, const int* in_sizes, int n_in,
                              void* d_out, int out_size, void* d_ws, size_t ws_size,
                              hipStream_t stream) {
    const float* buffer      = (const float*)d_in[0];
    const float* mlp_w       = (const float*)d_in[1];
    const float* ln_attn_w   = (const float*)d_in[2];
    const float* ln_attn_b   = (const float*)d_in[3];
    const float* ln_ffn_w    = (const float*)d_in[4];
    const float* ln_ffn_b    = (const float*)d_in[5];
    const float* qkv_w       = (const float*)d_in[6];
    const float* qkv_dw_w    = (const float*)d_in[7];
    const float* temperature = (const float*)d_in[8];
    const float* proj_attn_w = (const float*)d_in[9];
    const float* ffn_in_w    = (const float*)d_in[10];
    const float* ffn_dw_w    = (const float*)d_in[11];
    const float* ffn_out_w   = (const float*)d_in[12];
    const float* proj3d_w    = (const float*)d_in[13];

    char* wsb = (char*)d_ws;
    short* Wbf     = (short*)wsb;                 // 286208 bf16 weights
    short* mlpW    = Wbf;                         // [128][640] (padded taps)
    short* qkvW    = Wbf + 81920;                 // [384][128]
    short* projW   = Wbf + 131072;                // [128][128]
    short* ffnInW  = Wbf + 147456;                // [680][128]
    short* ffnOutW = Wbf + 234496;                // [128][340]
    short* p3dW    = Wbf + 278016;                // [64][128]
    float* wqT     = (float*)(wsb + 573440);      // [9][384] f32
    float* wgT     = (float*)(wsb + 587264);      // [9][680] f32
    short* PatchB  = (short*)(wsb + 611840);      // [M][640] bf16
    float* tok     = (float*)(wsb + 33379840);    // [M][128] f32
    short* LNbf    = (short*)(wsb + 46487040);    // [M][128] bf16
    short* QKVpre  = (short*)(wsb + 53040640);    // [M][384] bf16
    short* qkvb    = (short*)(wsb + 72701440);    // [M][384] bf16
    short* AObf    = (short*)(wsb + 92362240);    // [M][128] bf16
    short* F1      = (short*)(wsb + 98915840);    // [M][680] bf16
    short* G       = (short*)(wsb + 133731840);   // [M][344] bf16 (lda 344)

    dim3 blk(256);

    cvtw_k<<<1118, blk, 0, stream>>>(mlp_w, qkv_w, proj_attn_w, ffn_in_w, ffn_out_w, proj3d_w, Wbf);
    twp_k<<<38, blk, 0, stream>>>(qkv_dw_w, ffn_dw_w, wqT, wgT);
    unfold_k<<<6400, blk, 0, stream>>>(buffer, PatchB);

    // S2T: tok = patches @ mlp_w^T (f32 out), K padded to 640
    mm_k<false, false, false, false><<<dim3(200, 2), blk, 0, stream>>>(PatchB, mlpW, tok, M_TOK, 128, 640, 640);
    ln_k<<<6400, blk, 0, stream>>>(tok, ln_attn_w, ln_attn_b, LNbf);
    // qkv 1x1 (bf16 out)
    mm_k<false, false, true, false><<<dim3(200, 6), blk, 0, stream>>>(LNbf, qkvW, QKVpre, M_TOK, 384, 128, 128);
    // fused dwconv + l2norm
    dwl2n_k<<<4800, blk, 0, stream>>>(QKVpre, wqT, qkvb);
    attn_k<<<800, blk, 0, stream>>>(qkvb, temperature, AObf);
    // proj + residual
    mm_k<true, false, false, false><<<dim3(200, 2), blk, 0, stream>>>(AObf, projW, tok, M_TOK, 128, 128, 128);
    ln_k<<<6400, blk, 0, stream>>>(tok, ln_ffn_w, ln_ffn_b, LNbf);
    // ffn_in 1x1 (bf16 out)
    mm_k<false, false, true, false><<<dim3(200, 11), blk, 0, stream>>>(LNbf, ffnInW, F1, M_TOK, 680, 128, 128);
    // fused GDFN dwconv + gelu gate
    gdfn2_k<<<4300, blk, 0, stream>>>(F1, wgT, G);
    // ffn_out + residual (A lda = 344)
    mm_k<true, false, false, false><<<dim3(200, 2), blk, 0, stream>>>(G, ffnOutW, tok, M_TOK, 128, 340, 344);
    // Token2SAI (transposed product, coalesced)
    mm_k<false, true, false, true><<<dim3(200, 1), blk, 0, stream>>>(tok, p3dW, d_out, M_TOK, 64, 128, 128);
}